// Round 12
// baseline (457.564 us; speedup 1.0000x reference)
//
#include <hip/hip_runtime.h>

typedef unsigned short u16;
typedef __bf16 bf16x8 __attribute__((ext_vector_type(8)));
typedef float f32x4 __attribute__((ext_vector_type(4)));

// fp32 -> bf16 bits, round-to-nearest-even (finite inputs only)
__device__ __forceinline__ u16 f2bf(float f) {
  union { float f; unsigned u; } v; v.f = f;
  return (u16)((v.u + 0x7fffu + ((v.u >> 16) & 1u)) >> 16);
}
__device__ __forceinline__ float bf2f(u16 h) {
  union { unsigned u; float f; } v; v.u = ((unsigned)h) << 16;
  return v.f;
}

// pack two fp32 -> bf16x2 dword (round-half-up), low = lo, high = hi
__device__ __forceinline__ unsigned pkbf(float lo, float hi) {
  union { float f; unsigned u; } a, b; a.f = lo; b.f = hi;
  return __builtin_amdgcn_perm(b.u + 0x8000u, a.u + 0x8000u, 0x07060302u);
}

__device__ __forceinline__ float fexp2(float x) {
#if __has_builtin(__builtin_amdgcn_exp2f)
  return __builtin_amdgcn_exp2f(x);
#else
  return exp2f(x);
#endif
}

// async global->LDS, 16B per lane; LDS dst = base + lane*16 (wave-uniform base)
__device__ __forceinline__ void gld16(const u16* g, u16* l) {
  __builtin_amdgcn_global_load_lds(
      (const __attribute__((address_space(1))) void*)g,
      (__attribute__((address_space(3))) void*)l, 16, 0, 0);
}

// pi permutation of a key k in [0,64) -> position in vT 64-block / P^T k-slot:
// pos = (k&32) + ((k>>2)&3)*8 + ((k>>4)&1)*4 + (k&3)

// ---------------------------------------------------------------------------
// fp32 -> bf16 bulk convert for all three inputs in ONE dispatch.
// ---------------------------------------------------------------------------
__global__ __launch_bounds__(256) void cvt3(
    const float* __restrict__ x, const float* __restrict__ wa,
    const float* __restrict__ wp, u16* __restrict__ xb,
    u16* __restrict__ wab, u16* __restrict__ wpb)
{
  int b = blockIdx.x;
  const float* in; u16* out; int i;
  if (b < 2048)      { in = x;  out = xb;  i = b * 256 + threadIdx.x; }
  else if (b < 3584) { in = wa; out = wab; i = (b - 2048) * 256 + threadIdx.x; }
  else               { in = wp; out = wpb; i = (b - 3584) * 256 + threadIdx.x; }
  const float* p = in + (size_t)i * 8;
  float4 a = *(const float4*)p, c = *(const float4*)(p + 4);
  uint4 o;
  o.x = pkbf(a.x, a.y); o.y = pkbf(a.z, a.w);
  o.z = pkbf(c.x, c.y); o.w = pkbf(c.z, c.w);
  *(uint4*)&out[(size_t)i * 8] = o;
}

// ---------------------------------------------------------------------------
// combine: y = (O0 + O1) / (l0 + l1).  O* are bf16 unnormalized partials
// [4096][1024]; l* are fp32 [4096][16] (per row,head). 8 elems/thread.
// ---------------------------------------------------------------------------
__global__ __launch_bounds__(256) void combine2(
    const u16* __restrict__ O0, const u16* __restrict__ O1,
    const float* __restrict__ l0, const float* __restrict__ l1,
    u16* __restrict__ y)
{
  int i = blockIdx.x * 256 + threadIdx.x;          // 524288 threads
  int e0 = i * 8;
  int row = e0 >> 10, h = (e0 & 1023) >> 6;
  float inv = 1.0f / (l0[row * 16 + h] + l1[row * 16 + h]);
  uint4 a = *(const uint4*)&O0[(size_t)e0];
  uint4 b = *(const uint4*)&O1[(size_t)e0];
  unsigned aw[4] = {a.x, a.y, a.z, a.w}, bw[4] = {b.x, b.y, b.z, b.w};
  uint4 o;
  unsigned ow[4];
#pragma unroll
  for (int j = 0; j < 4; ++j) {
    float lo = (bf2f((u16)(aw[j] & 0xffffu)) + bf2f((u16)(bw[j] & 0xffffu))) * inv;
    float hi = (bf2f((u16)(aw[j] >> 16))     + bf2f((u16)(bw[j] >> 16)))     * inv;
    ow[j] = pkbf(lo, hi);
  }
  o.x = ow[0]; o.y = ow[1]; o.z = ow[2]; o.w = ow[3];
  *(uint4*)&y[(size_t)e0] = o;
}

// ---------------------------------------------------------------------------
// m97-style GEMM: C[M,N] = A[M,K]*B[N,K]^T, bf16 in, fp32 acc.
// VSPLIT: n0>=2048 blocks write V TRANSPOSED to C2 (vT[1024][4096]) in
// pi-permuted key order.
// ---------------------------------------------------------------------------
template<bool COUT_F32, bool VSPLIT>
__global__ __launch_bounds__(256, 3) void gemm_lds(
    const u16* __restrict__ A, const u16* __restrict__ B, void* __restrict__ C,
    u16* __restrict__ C2, int M, int N, int K, int ldc)
{
  __shared__ u16 S[9216];
  u16* As = S;
  u16* Bs = S + 4096;
  const int tid  = threadIdx.x;
  const int wave = tid >> 6, lane = tid & 63;
  const int quad = lane >> 4, ln = lane & 15;
  const int m0 = blockIdx.y * 128, n0 = blockIdx.x * 128;
  const int wm = (wave >> 1) * 64, wn = (wave & 1) * 64;

  const int srow = wave * 32 + (lane >> 2);
  const int scol = (lane & 3) * 8;

  f32x4 acc[4][4] = {};

  for (int k0 = 0; k0 < K; k0 += 32) {
    __syncthreads();
    const u16* ga = A + (size_t)(m0 + srow) * K + k0 + scol;
    const u16* gb = B + (size_t)(n0 + srow) * K + k0 + scol;
    gld16(ga,                  As + wave * 1024);
    gld16(ga + (size_t)16 * K, As + wave * 1024 + 512);
    gld16(gb,                  Bs + wave * 1024);
    gld16(gb + (size_t)16 * K, Bs + wave * 1024 + 512);
    __syncthreads();

    bf16x8 af[4], bfr[4];
#pragma unroll
    for (int i = 0; i < 4; ++i) af[i]  = *(const bf16x8*)&As[(wm + i * 16 + ln) * 32 + quad * 8];
#pragma unroll
    for (int j = 0; j < 4; ++j) bfr[j] = *(const bf16x8*)&Bs[(wn + j * 16 + ln) * 32 + quad * 8];
#pragma unroll
    for (int i = 0; i < 4; ++i)
#pragma unroll
      for (int j = 0; j < 4; ++j)
        acc[i][j] = __builtin_amdgcn_mfma_f32_16x16x32_bf16(af[i], bfr[j], acc[i][j], 0, 0, 0);
  }

  if constexpr (VSPLIT) {
    if (n0 >= 2048) {
      u16 (*Cs)[72] = (u16(*)[72])S;
      __syncthreads();
#pragma unroll
      for (int c = 0; c < 2; ++c) {
        if ((wave >> 1) == c) {
#pragma unroll
          for (int i = 0; i < 4; ++i)
#pragma unroll
            for (int j = 0; j < 4; ++j)
#pragma unroll
              for (int r = 0; r < 4; ++r) {
                int pos = (i >> 1) * 32 + quad * 8 + (i & 1) * 4 + r;  // pi(m-in-chunk)
                Cs[wn + j * 16 + ln][pos] = f2bf(acc[i][j][r]);
              }
        }
        __syncthreads();
        {
          int nl = tid >> 1, mseg = (tid & 1) * 32;
#pragma unroll
          for (int s2 = 0; s2 < 4; ++s2) {
            uint4 v4 = *(const uint4*)&Cs[nl][mseg + s2 * 8];
            *(uint4*)&C2[(size_t)(n0 - 2048 + nl) * 4096 + m0 + c * 64 + mseg + s2 * 8] = v4;
          }
        }
        __syncthreads();
      }
      return;
    }
  }

#pragma unroll
  for (int i = 0; i < 4; ++i)
#pragma unroll
    for (int j = 0; j < 4; ++j)
#pragma unroll
      for (int r = 0; r < 4; ++r) {
        int m = m0 + wm + i * 16 + quad * 4 + r;   // C/D: row = quad*4+reg
        int n = n0 + wn + j * 16 + ln;             //      col = lane&15
        if constexpr (COUT_F32)
          ((float*)C)[(size_t)m * ldc + n] = acc[i][j][r];
        else
          ((u16*)C)[(size_t)m * ldc + n] = f2bf(acc[i][j][r]);
      }
}

// ---------------------------------------------------------------------------
// 64x64-tile GEMM for GEMM2 (latency-bound -> 4 blocks/CU).
// ---------------------------------------------------------------------------
template<bool COUT_F32>
__global__ __launch_bounds__(256, 4) void gemm_t64(
    const u16* __restrict__ A, const u16* __restrict__ B, void* __restrict__ C,
    int M, int N, int K, int ldc)
{
  __shared__ u16 S[4096];            // As[64][32]@0, Bs[64][32]@2048
  u16* As = S;
  u16* Bs = S + 2048;
  const int tid  = threadIdx.x;
  const int wave = tid >> 6, lane = tid & 63;
  const int quad = lane >> 4, ln = lane & 15;
  const int m0 = blockIdx.y * 64, n0 = blockIdx.x * 64;

  const int srow = wave * 16 + (lane >> 2);
  const int scol = (lane & 3) * 8;

  f32x4 acc[4] = {};

  for (int k0 = 0; k0 < K; k0 += 32) {
    __syncthreads();
    gld16(A + (size_t)(m0 + srow) * K + k0 + scol, As + wave * 512);
    gld16(B + (size_t)(n0 + srow) * K + k0 + scol, Bs + wave * 512);
    __syncthreads();

    bf16x8 af = *(const bf16x8*)&As[(wave * 16 + ln) * 32 + quad * 8];
#pragma unroll
    for (int j = 0; j < 4; ++j) {
      bf16x8 bf = *(const bf16x8*)&Bs[(j * 16 + ln) * 32 + quad * 8];
      acc[j] = __builtin_amdgcn_mfma_f32_16x16x32_bf16(af, bf, acc[j], 0, 0, 0);
    }
  }

#pragma unroll
  for (int j = 0; j < 4; ++j)
#pragma unroll
    for (int r = 0; r < 4; ++r) {
      int m = m0 + wave * 16 + quad * 4 + r;
      int n = n0 + j * 16 + ln;
      if constexpr (COUT_F32)
        ((float*)C)[(size_t)m * ldc + n] = acc[j][r];
      else
        ((u16*)C)[(size_t)m * ldc + n] = f2bf(acc[j][r]);
    }
}

// ---------------------------------------------------------------------------
// Fallback GEMM (fp32 staging) — used only if ws_size < 40 MiB.
// ---------------------------------------------------------------------------
template<bool F32>
__device__ __forceinline__ void stage8(u16* dst, const void* base, size_t off) {
  if constexpr (F32) {
    const float* p = (const float*)base + off;
    float4 a = *(const float4*)p;
    float4 b = *(const float4*)(p + 4);
    uint4 q;
    q.x = pkbf(a.x, a.y); q.y = pkbf(a.z, a.w);
    q.z = pkbf(b.x, b.y); q.w = pkbf(b.z, b.w);
    *(uint4*)dst = q;
  } else {
    *(uint4*)dst = *(const uint4*)((const u16*)base + off);
  }
}

template<bool AF32, bool BF32, bool COUT_F32, bool VSPLIT>
__global__ __launch_bounds__(256) void gemm_bt(
    const void* __restrict__ A, const void* __restrict__ B, void* __restrict__ C,
    u16* __restrict__ C2, int M, int N, int K, int ldc)
{
  __shared__ u16 As[128][40];
  __shared__ u16 Bs[128][40];
  const int tid  = threadIdx.x;
  const int wave = tid >> 6, lane = tid & 63;
  const int quad = lane >> 4, ln = lane & 15;
  const int m0 = blockIdx.y * 128, n0 = blockIdx.x * 128;
  const int wm = (wave >> 1) * 64, wn = (wave & 1) * 64;

  f32x4 acc[4][4] = {};

  for (int k0 = 0; k0 < K; k0 += 32) {
    __syncthreads();
#pragma unroll
    for (int i = 0; i < 2; ++i) {
      int idx = tid + i * 256;
      int row = idx >> 2, seg = (idx & 3) * 8;
      stage8<AF32>(&As[row][seg], A, (size_t)(m0 + row) * K + k0 + seg);
      stage8<BF32>(&Bs[row][seg], B, (size_t)(n0 + row) * K + k0 + seg);
    }
    __syncthreads();
    bf16x8 af[4], bfr[4];
#pragma unroll
    for (int i = 0; i < 4; ++i) af[i]  = *(const bf16x8*)&As[wm + i * 16 + ln][quad * 8];
#pragma unroll
    for (int j = 0; j < 4; ++j) bfr[j] = *(const bf16x8*)&Bs[wn + j * 16 + ln][quad * 8];
#pragma unroll
    for (int i = 0; i < 4; ++i)
#pragma unroll
      for (int j = 0; j < 4; ++j)
        acc[i][j] = __builtin_amdgcn_mfma_f32_16x16x32_bf16(af[i], bfr[j], acc[i][j], 0, 0, 0);
  }

  if constexpr (VSPLIT) {
    if (n0 >= 2048) {
      __shared__ u16 Cs[128][72];
#pragma unroll
      for (int c = 0; c < 2; ++c) {
        if ((wave >> 1) == c) {
#pragma unroll
          for (int i = 0; i < 4; ++i)
#pragma unroll
            for (int j = 0; j < 4; ++j)
#pragma unroll
              for (int r = 0; r < 4; ++r) {
                int pos = (i >> 1) * 32 + quad * 8 + (i & 1) * 4 + r;
                Cs[wn + j * 16 + ln][pos] = f2bf(acc[i][j][r]);
              }
        }
        __syncthreads();
        {
          int nl = tid >> 1, mseg = (tid & 1) * 32;
#pragma unroll
          for (int s2 = 0; s2 < 4; ++s2) {
            uint4 v4 = *(const uint4*)&Cs[nl][mseg + s2 * 8];
            *(uint4*)&C2[(size_t)(n0 - 2048 + nl) * 4096 + m0 + c * 64 + mseg + s2 * 8] = v4;
          }
        }
        __syncthreads();
      }
      return;
    }
  }

#pragma unroll
  for (int i = 0; i < 4; ++i)
#pragma unroll
    for (int j = 0; j < 4; ++j)
#pragma unroll
      for (int r = 0; r < 4; ++r) {
        int m = m0 + wm + i * 16 + quad * 4 + r;
        int n = n0 + wn + j * 16 + ln;
        if constexpr (COUT_F32)
          ((float*)C)[(size_t)m * ldc + n] = acc[i][j][r];
        else
          ((u16*)C)[(size_t)m * ldc + n] = f2bf(acc[i][j][r]);
      }
}

// ---------------------------------------------------------------------------
// Causal flash attention (MFMA), fixed-base softmax (linearly decomposable!),
// transposed score path (S^T = K·Q^T, in-register P^T B-frag, O^T = V^T·P^T).
// Q-tile 128 (2 strips/wave), K-tile 64, register-prefetch double buffer.
// SPLIT: grid 1024 = 32 qt x 2 key-halves x 16 heads, 4 blocks/CU;
//   half0 kt in [0,qt], half1 kt in [qt+1, 2qt+1] (qt+1 tiles each, LPT order);
//   writes bf16 unnormalized O-partial + fp32 l-partial; combine2 finishes.
// !SPLIT: grid 512, full range, writes normalized y (R11 behavior).
// ---------------------------------------------------------------------------
struct StageRegs { uint4 k0, k1, v0, v1; };

__device__ __forceinline__ StageRegs attn_stage_load(
    const u16* __restrict__ qk, const u16* __restrict__ vT,
    int h, int kbase, int tid) {
  StageRegs s;
  {
    int key = tid >> 2, seg = (tid & 3) * 16;
    const u16* kp = qk + (size_t)(kbase + key) * 2048 + 1024 + h * 64 + seg;
    s.k0 = *(const uint4*)kp;
    s.k1 = *(const uint4*)(kp + 8);
  }
  {
    int kh = tid >> 7, d = (tid >> 1) & 63, sg = (tid & 1) * 16;
    const u16* vp = vT + (size_t)(h * 64 + d) * 4096 + kbase + kh * 32 + sg;
    s.v0 = *(const uint4*)vp;
    s.v1 = *(const uint4*)(vp + 8);
  }
  return s;
}

template<bool SPLIT>
__global__ __launch_bounds__(256, SPLIT ? 4 : 2) void attn_fwd(
    const u16* __restrict__ qk, const u16* __restrict__ vT,
    u16* __restrict__ out0, u16* __restrict__ out1,
    float* __restrict__ l0buf, float* __restrict__ l1buf)
{
  __shared__ u16 Ks[2][2][64][40];     // [buf][d-half][key][d%32] pad 40
  __shared__ u16 Vt[2][2][64][40];     // [buf][pi-key-half][d][pos%32]

  const int tid  = threadIdx.x;
  const int wave = tid >> 6, lane = tid & 63;
  const int quad = lane >> 4, ln = lane & 15;
  const int bx = blockIdx.x;
  int qt, h, ktb, kte;
  u16* oout; float* lout;
  if constexpr (SPLIT) {
    qt = 31 - (bx >> 5);               // heavy chunks (qt+1 iters) first
    int half = (bx >> 4) & 1;
    h = bx & 15;
    ktb = half ? (qt + 1) : 0;
    kte = half ? (2 * qt + 1) : qt;
    oout = half ? out1 : out0;
    lout = half ? l1buf : l0buf;
  } else {
    qt = (bx < 256) ? (31 - (bx >> 4)) : ((bx - 256) >> 4);
    h = bx & 15;
    ktb = 0; kte = 2 * qt + 1;
    oout = out0; lout = nullptr;
  }
  const float C1 = 0.18033688f;        // 0.125 * log2(e)

  const int sq0[2] = { qt * 128 + wave * 32, qt * 128 + wave * 32 + 16 };

  bf16x8 qa[2][2];
#pragma unroll
  for (int s = 0; s < 2; ++s) {
    const u16* qrow = qk + (size_t)(sq0[s] + ln) * 2048 + h * 64;
    qa[s][0] = *(const bf16x8*)(qrow + quad * 8);
    qa[s][1] = *(const bf16x8*)(qrow + 32 + quad * 8);
  }

  f32x4 o[2][4] = {};                  // O^T tiles: [strip][d-tile]; row=d, col=qrow
  float l_i[2] = {0.f, 0.f};           // per-lane partial l for qrow=ln

  StageRegs st = attn_stage_load(qk, vT, h, ktb * 64, tid);
  int b = 0;
  for (int kt = ktb; kt <= kte; ++kt, b ^= 1) {
    {
      int key = tid >> 2, seg = (tid & 3) * 16;
      int kh = seg >> 5, off = seg & 31;
      *(uint4*)&Ks[b][kh][key][off]     = st.k0;
      *(uint4*)&Ks[b][kh][key][off + 8] = st.k1;
      int vh = tid >> 7, d = (tid >> 1) & 63, sg = (tid & 1) * 16;
      *(uint4*)&Vt[b][vh][d][sg]     = st.v0;
      *(uint4*)&Vt[b][vh][d][sg + 8] = st.v1;
    }
    __syncthreads();
    if (kt < kte) st = attn_stage_load(qk, vT, h, (kt + 1) * 64, tid);

    bf16x8 kf[2][4], vb[2][4];
#pragma unroll
    for (int hf = 0; hf < 2; ++hf)
#pragma unroll
      for (int c = 0; c < 4; ++c) {
        kf[hf][c] = *(const bf16x8*)&Ks[b][hf][c * 16 + ln][quad * 8];
        vb[hf][c] = *(const bf16x8*)&Vt[b][hf][c * 16 + ln][quad * 8];
      }

    bool act[2];
#pragma unroll
    for (int s = 0; s < 2; ++s) act[s] = (kt * 64 <= sq0[s] + 15);

    bf16x8 pb[2][2];
#pragma unroll
    for (int s = 0; s < 2; ++s) {
      if (!act[s]) continue;           // wave-uniform
      f32x4 sv[4];
#pragma unroll
      for (int t = 0; t < 4; ++t) {
        f32x4 z = {0.f, 0.f, 0.f, 0.f};
        z = __builtin_amdgcn_mfma_f32_16x16x32_bf16(kf[0][t], qa[s][0], z, 0, 0, 0);
        z = __builtin_amdgcn_mfma_f32_16x16x32_bf16(kf[1][t], qa[s][1], z, 0, 0, 0);
        sv[t] = z;                     // row=key=t*16+quad*4+r, col=qrow=ln
      }
      float p[4][4];                   // [t][r]
      if (kt * 64 + 63 > sq0[s]) {
        const int qr = sq0[s] + ln;
#pragma unroll
        for (int t = 0; t < 4; ++t) {
          int keyb = kt * 64 + t * 16 + quad * 4;
#pragma unroll
          for (int r = 0; r < 4; ++r) {
            float arg = (keyb + r > qr) ? -200.0f : fmaf(sv[t][r], C1, -46.0f);
            p[t][r] = fexp2(arg);
          }
        }
      } else {
#pragma unroll
        for (int t = 0; t < 4; ++t)
#pragma unroll
          for (int r = 0; r < 4; ++r)
            p[t][r] = fexp2(fmaf(sv[t][r], C1, -46.0f));
      }
#pragma unroll
      for (int t = 0; t < 4; ++t)
        l_i[s] += (p[t][0] + p[t][1]) + (p[t][2] + p[t][3]);
#pragma unroll
      for (int H = 0; H < 2; ++H) {
        union { unsigned u[4]; bf16x8 v; } pk;
        pk.u[0] = pkbf(p[2 * H][0],     p[2 * H][1]);
        pk.u[1] = pkbf(p[2 * H][2],     p[2 * H][3]);
        pk.u[2] = pkbf(p[2 * H + 1][0], p[2 * H + 1][1]);
        pk.u[3] = pkbf(p[2 * H + 1][2], p[2 * H + 1][3]);
        pb[s][H] = pk.v;
      }
    }

#pragma unroll
    for (int s = 0; s < 2; ++s) {
      if (!act[s]) continue;
#pragma unroll
      for (int dt = 0; dt < 4; ++dt) {
        f32x4 z = o[s][dt];
        z = __builtin_amdgcn_mfma_f32_16x16x32_bf16(vb[0][dt], pb[s][0], z, 0, 0, 0);
        z = __builtin_amdgcn_mfma_f32_16x16x32_bf16(vb[1][dt], pb[s][1], z, 0, 0, 0);
        o[s][dt] = z;
      }
    }
  }

#pragma unroll
  for (int s = 0; s < 2; ++s) {
    l_i[s] += __shfl_xor(l_i[s], 16);
    l_i[s] += __shfl_xor(l_i[s], 32);
    int rowg = sq0[s] + ln;
    if constexpr (SPLIT) {
      // unnormalized bf16 partial + fp32 l partial (quad 0 stores l once)
#pragma unroll
      for (int dt = 0; dt < 4; ++dt)
#pragma unroll
        for (int r = 0; r < 4; ++r)
          oout[(size_t)rowg * 1024 + h * 64 + dt * 16 + quad * 4 + r] = f2bf(o[s][dt][r]);
      if (quad == 0) lout[rowg * 16 + h] = l_i[s];
    } else {
      float inv = 1.0f / l_i[s];
#pragma unroll
      for (int dt = 0; dt < 4; ++dt)
#pragma unroll
        for (int r = 0; r < 4; ++r)
          oout[(size_t)rowg * 1024 + h * 64 + dt * 16 + quad * 4 + r] = f2bf(o[s][dt][r] * inv);
    }
  }
}

extern "C" void kernel_launch(void* const* d_in, const int* in_sizes, int n_in,
                              void* d_out, int out_size, void* d_ws, size_t ws_size,
                              hipStream_t stream) {
  const float* x      = (const float*)d_in[0];   // [4096,1024] fp32
  const float* w_attn = (const float*)d_in[1];   // [3072,1024] fp32
  const float* w_proj = (const float*)d_in[2];   // [1024,1024] fp32

  char* ws = (char*)d_ws;
  u16* qk = (u16*)ws;                        // 16 MiB [4096][2048]
  u16* vT = (u16*)(ws + (16u << 20));        //  8 MiB [1024][4096] pi-permuted

  if (ws_size >= (size_t)(44u << 20)) {
    // Path A: key-split attention with partial combine. Peak 42.25 MiB.
    u16*   wpb = (u16*)(ws + (24u << 20));   //  2 MiB bf16 w_proj
    u16*   xb  = (u16*)(ws + (26u << 20));   //  8 MiB bf16 x       (dead after GEMM1)
    u16*   wab = (u16*)(ws + (34u << 20));   //  6 MiB bf16 w_attn  (dead after GEMM1)
    u16*   Op0 = (u16*)(ws + (26u << 20));   //  8 MiB bf16 O-partial half0 (overlays xb)
    u16*   Op1 = (u16*)(ws + (34u << 20));   //  8 MiB bf16 O-partial half1 (overlays wab + 2 MiB)
    float* l0  = (float*)(ws + (42u << 20));            // 256 KiB
    float* l1  = (float*)(ws + (42u << 20) + (256u << 10)); // 256 KiB
    u16*   y   = (u16*)ws;                   //  8 MiB, overlays qk (dead after attn)

    cvt3<<<4096, 256, 0, stream>>>(x, w_attn, w_proj, xb, wab, wpb);
    gemm_lds<false, true><<<dim3(24, 32), 256, 0, stream>>>(
        xb, wab, qk, vT, 4096, 3072, 1024, 2048);
    attn_fwd<true><<<dim3(1024), 256, 0, stream>>>(qk, vT, Op0, Op1, l0, l1);
    combine2<<<2048, 256, 0, stream>>>(Op0, Op1, l0, l1, y);
    gemm_t64<true><<<dim3(16, 64), 256, 0, stream>>>(
        y, wpb, d_out, 4096, 1024, 1024, 1024);
  } else if (ws_size >= (size_t)(40u << 20)) {
    // Path B: R11 behavior.
    u16* wpb = (u16*)(ws + (24u << 20));
    u16* xb  = (u16*)(ws + (26u << 20));
    u16* wab = (u16*)(ws + (34u << 20));
    u16* y   = (u16*)(ws + (26u << 20));

    cvt3<<<4096, 256, 0, stream>>>(x, w_attn, w_proj, xb, wab, wpb);
    gemm_lds<false, true><<<dim3(24, 32), 256, 0, stream>>>(
        xb, wab, qk, vT, 4096, 3072, 1024, 2048);
    attn_fwd<false><<<dim3(512), 256, 0, stream>>>(qk, vT, y, nullptr, nullptr, nullptr);
    gemm_t64<true><<<dim3(16, 64), 256, 0, stream>>>(
        y, wpb, d_out, 4096, 1024, 1024, 1024);
  } else {
    // Path C: fp32-staging fallback.
    u16* y = (u16*)(ws + (24u << 20));
    gemm_bt<true, true, false, true><<<dim3(24, 32), 256, 0, stream>>>(
        x, w_attn, qk, vT, 4096, 3072, 1024, 2048);
    attn_fwd<false><<<dim3(512), 256, 0, stream>>>(qk, vT, y, nullptr, nullptr, nullptr);
    gemm_bt<false, true, true, false><<<dim3(8, 32), 256, 0, stream>>>(
        y, w_proj, d_out, nullptr, 4096, 1024, 1024, 1024);
  }
}

// Round 13
// 251.944 us; speedup vs baseline: 1.8161x; 1.8161x over previous
//
#include <hip/hip_runtime.h>

typedef unsigned short u16;
typedef __bf16 bf16x8 __attribute__((ext_vector_type(8)));
typedef float f32x4 __attribute__((ext_vector_type(4)));

// fp32 -> bf16 bits, round-to-nearest-even (finite inputs only)
__device__ __forceinline__ u16 f2bf(float f) {
  union { float f; unsigned u; } v; v.f = f;
  return (u16)((v.u + 0x7fffu + ((v.u >> 16) & 1u)) >> 16);
}
__device__ __forceinline__ float bf2f(u16 h) {
  union { unsigned u; float f; } v; v.u = ((unsigned)h) << 16;
  return v.f;
}

// pack two fp32 -> bf16x2 dword (round-half-up), low = lo, high = hi
__device__ __forceinline__ unsigned pkbf(float lo, float hi) {
  union { float f; unsigned u; } a, b; a.f = lo; b.f = hi;
  return __builtin_amdgcn_perm(b.u + 0x8000u, a.u + 0x8000u, 0x07060302u);
}

__device__ __forceinline__ float fexp2(float x) {
#if __has_builtin(__builtin_amdgcn_exp2f)
  return __builtin_amdgcn_exp2f(x);
#else
  return exp2f(x);
#endif
}

// async global->LDS, 16B per lane; LDS dst = base + lane*16 (wave-uniform base)
__device__ __forceinline__ void gld16(const u16* g, u16* l) {
  __builtin_amdgcn_global_load_lds(
      (const __attribute__((address_space(1))) void*)g,
      (__attribute__((address_space(3))) void*)l, 16, 0, 0);
}

// pi permutation of a key k in [0,64) -> position in vT 64-block / P^T k-slot:
// pos = (k&32) + ((k>>2)&3)*8 + ((k>>4)&1)*4 + (k&3)

// ---------------------------------------------------------------------------
// fp32 -> bf16 bulk convert for all three inputs in ONE dispatch.
// ---------------------------------------------------------------------------
__global__ __launch_bounds__(256) void cvt3(
    const float* __restrict__ x, const float* __restrict__ wa,
    const float* __restrict__ wp, u16* __restrict__ xb,
    u16* __restrict__ wab, u16* __restrict__ wpb)
{
  int b = blockIdx.x;
  const float* in; u16* out; int i;
  if (b < 2048)      { in = x;  out = xb;  i = b * 256 + threadIdx.x; }
  else if (b < 3584) { in = wa; out = wab; i = (b - 2048) * 256 + threadIdx.x; }
  else               { in = wp; out = wpb; i = (b - 3584) * 256 + threadIdx.x; }
  const float* p = in + (size_t)i * 8;
  float4 a = *(const float4*)p, c = *(const float4*)(p + 4);
  uint4 o;
  o.x = pkbf(a.x, a.y); o.y = pkbf(a.z, a.w);
  o.z = pkbf(c.x, c.y); o.w = pkbf(c.z, c.w);
  *(uint4*)&out[(size_t)i * 8] = o;
}

// ---------------------------------------------------------------------------
// combine: y = (O0 + O1) / (l0 + l1).  O* are bf16 unnormalized partials
// [4096][1024]; l* are fp32 [4096][16] (per row,head). 8 elems/thread.
// ---------------------------------------------------------------------------
__global__ __launch_bounds__(256) void combine2(
    const u16* __restrict__ O0, const u16* __restrict__ O1,
    const float* __restrict__ l0, const float* __restrict__ l1,
    u16* __restrict__ y)
{
  int i = blockIdx.x * 256 + threadIdx.x;          // 524288 threads
  int e0 = i * 8;
  int row = e0 >> 10, h = (e0 & 1023) >> 6;
  float inv = 1.0f / (l0[row * 16 + h] + l1[row * 16 + h]);
  uint4 a = *(const uint4*)&O0[(size_t)e0];
  uint4 b = *(const uint4*)&O1[(size_t)e0];
  unsigned aw[4] = {a.x, a.y, a.z, a.w}, bw[4] = {b.x, b.y, b.z, b.w};
  uint4 o;
  unsigned ow[4];
#pragma unroll
  for (int j = 0; j < 4; ++j) {
    float lo = (bf2f((u16)(aw[j] & 0xffffu)) + bf2f((u16)(bw[j] & 0xffffu))) * inv;
    float hi = (bf2f((u16)(aw[j] >> 16))     + bf2f((u16)(bw[j] >> 16)))     * inv;
    ow[j] = pkbf(lo, hi);
  }
  o.x = ow[0]; o.y = ow[1]; o.z = ow[2]; o.w = ow[3];
  *(uint4*)&y[(size_t)e0] = o;
}

// ---------------------------------------------------------------------------
// m97-style GEMM: C[M,N] = A[M,K]*B[N,K]^T, bf16 in, fp32 acc.
// VSPLIT: n0>=2048 blocks write V TRANSPOSED to C2 (vT[1024][4096]) in
// pi-permuted key order.
// ---------------------------------------------------------------------------
template<bool COUT_F32, bool VSPLIT>
__global__ __launch_bounds__(256, 3) void gemm_lds(
    const u16* __restrict__ A, const u16* __restrict__ B, void* __restrict__ C,
    u16* __restrict__ C2, int M, int N, int K, int ldc)
{
  __shared__ u16 S[9216];
  u16* As = S;
  u16* Bs = S + 4096;
  const int tid  = threadIdx.x;
  const int wave = tid >> 6, lane = tid & 63;
  const int quad = lane >> 4, ln = lane & 15;
  const int m0 = blockIdx.y * 128, n0 = blockIdx.x * 128;
  const int wm = (wave >> 1) * 64, wn = (wave & 1) * 64;

  const int srow = wave * 32 + (lane >> 2);
  const int scol = (lane & 3) * 8;

  f32x4 acc[4][4] = {};

  for (int k0 = 0; k0 < K; k0 += 32) {
    __syncthreads();
    const u16* ga = A + (size_t)(m0 + srow) * K + k0 + scol;
    const u16* gb = B + (size_t)(n0 + srow) * K + k0 + scol;
    gld16(ga,                  As + wave * 1024);
    gld16(ga + (size_t)16 * K, As + wave * 1024 + 512);
    gld16(gb,                  Bs + wave * 1024);
    gld16(gb + (size_t)16 * K, Bs + wave * 1024 + 512);
    __syncthreads();

    bf16x8 af[4], bfr[4];
#pragma unroll
    for (int i = 0; i < 4; ++i) af[i]  = *(const bf16x8*)&As[(wm + i * 16 + ln) * 32 + quad * 8];
#pragma unroll
    for (int j = 0; j < 4; ++j) bfr[j] = *(const bf16x8*)&Bs[(wn + j * 16 + ln) * 32 + quad * 8];
#pragma unroll
    for (int i = 0; i < 4; ++i)
#pragma unroll
      for (int j = 0; j < 4; ++j)
        acc[i][j] = __builtin_amdgcn_mfma_f32_16x16x32_bf16(af[i], bfr[j], acc[i][j], 0, 0, 0);
  }

  if constexpr (VSPLIT) {
    if (n0 >= 2048) {
      u16 (*Cs)[72] = (u16(*)[72])S;
      __syncthreads();
#pragma unroll
      for (int c = 0; c < 2; ++c) {
        if ((wave >> 1) == c) {
#pragma unroll
          for (int i = 0; i < 4; ++i)
#pragma unroll
            for (int j = 0; j < 4; ++j)
#pragma unroll
              for (int r = 0; r < 4; ++r) {
                int pos = (i >> 1) * 32 + quad * 8 + (i & 1) * 4 + r;  // pi(m-in-chunk)
                Cs[wn + j * 16 + ln][pos] = f2bf(acc[i][j][r]);
              }
        }
        __syncthreads();
        {
          int nl = tid >> 1, mseg = (tid & 1) * 32;
#pragma unroll
          for (int s2 = 0; s2 < 4; ++s2) {
            uint4 v4 = *(const uint4*)&Cs[nl][mseg + s2 * 8];
            *(uint4*)&C2[(size_t)(n0 - 2048 + nl) * 4096 + m0 + c * 64 + mseg + s2 * 8] = v4;
          }
        }
        __syncthreads();
      }
      return;
    }
  }

#pragma unroll
  for (int i = 0; i < 4; ++i)
#pragma unroll
    for (int j = 0; j < 4; ++j)
#pragma unroll
      for (int r = 0; r < 4; ++r) {
        int m = m0 + wm + i * 16 + quad * 4 + r;   // C/D: row = quad*4+reg
        int n = n0 + wn + j * 16 + ln;             //      col = lane&15
        if constexpr (COUT_F32)
          ((float*)C)[(size_t)m * ldc + n] = acc[i][j][r];
        else
          ((u16*)C)[(size_t)m * ldc + n] = f2bf(acc[i][j][r]);
      }
}

// ---------------------------------------------------------------------------
// 64x64-tile GEMM for GEMM2 (latency-bound -> 4 blocks/CU).
// ---------------------------------------------------------------------------
template<bool COUT_F32>
__global__ __launch_bounds__(256, 4) void gemm_t64(
    const u16* __restrict__ A, const u16* __restrict__ B, void* __restrict__ C,
    int M, int N, int K, int ldc)
{
  __shared__ u16 S[4096];            // As[64][32]@0, Bs[64][32]@2048
  u16* As = S;
  u16* Bs = S + 2048;
  const int tid  = threadIdx.x;
  const int wave = tid >> 6, lane = tid & 63;
  const int quad = lane >> 4, ln = lane & 15;
  const int m0 = blockIdx.y * 64, n0 = blockIdx.x * 64;

  const int srow = wave * 16 + (lane >> 2);
  const int scol = (lane & 3) * 8;

  f32x4 acc[4] = {};

  for (int k0 = 0; k0 < K; k0 += 32) {
    __syncthreads();
    gld16(A + (size_t)(m0 + srow) * K + k0 + scol, As + wave * 512);
    gld16(B + (size_t)(n0 + srow) * K + k0 + scol, Bs + wave * 512);
    __syncthreads();

    bf16x8 af = *(const bf16x8*)&As[(wave * 16 + ln) * 32 + quad * 8];
#pragma unroll
    for (int j = 0; j < 4; ++j) {
      bf16x8 bf = *(const bf16x8*)&Bs[(j * 16 + ln) * 32 + quad * 8];
      acc[j] = __builtin_amdgcn_mfma_f32_16x16x32_bf16(af, bf, acc[j], 0, 0, 0);
    }
  }

#pragma unroll
  for (int j = 0; j < 4; ++j)
#pragma unroll
    for (int r = 0; r < 4; ++r) {
      int m = m0 + wave * 16 + quad * 4 + r;
      int n = n0 + j * 16 + ln;
      if constexpr (COUT_F32)
        ((float*)C)[(size_t)m * ldc + n] = acc[j][r];
      else
        ((u16*)C)[(size_t)m * ldc + n] = f2bf(acc[j][r]);
    }
}

// ---------------------------------------------------------------------------
// Fallback GEMM (fp32 staging) — used only if ws_size < 40 MiB.
// ---------------------------------------------------------------------------
template<bool F32>
__device__ __forceinline__ void stage8(u16* dst, const void* base, size_t off) {
  if constexpr (F32) {
    const float* p = (const float*)base + off;
    float4 a = *(const float4*)p;
    float4 b = *(const float4*)(p + 4);
    uint4 q;
    q.x = pkbf(a.x, a.y); q.y = pkbf(a.z, a.w);
    q.z = pkbf(b.x, b.y); q.w = pkbf(b.z, b.w);
    *(uint4*)dst = q;
  } else {
    *(uint4*)dst = *(const uint4*)((const u16*)base + off);
  }
}

template<bool AF32, bool BF32, bool COUT_F32, bool VSPLIT>
__global__ __launch_bounds__(256) void gemm_bt(
    const void* __restrict__ A, const void* __restrict__ B, void* __restrict__ C,
    u16* __restrict__ C2, int M, int N, int K, int ldc)
{
  __shared__ u16 As[128][40];
  __shared__ u16 Bs[128][40];
  const int tid  = threadIdx.x;
  const int wave = tid >> 6, lane = tid & 63;
  const int quad = lane >> 4, ln = lane & 15;
  const int m0 = blockIdx.y * 128, n0 = blockIdx.x * 128;
  const int wm = (wave >> 1) * 64, wn = (wave & 1) * 64;

  f32x4 acc[4][4] = {};

  for (int k0 = 0; k0 < K; k0 += 32) {
    __syncthreads();
#pragma unroll
    for (int i = 0; i < 2; ++i) {
      int idx = tid + i * 256;
      int row = idx >> 2, seg = (idx & 3) * 8;
      stage8<AF32>(&As[row][seg], A, (size_t)(m0 + row) * K + k0 + seg);
      stage8<BF32>(&Bs[row][seg], B, (size_t)(n0 + row) * K + k0 + seg);
    }
    __syncthreads();
    bf16x8 af[4], bfr[4];
#pragma unroll
    for (int i = 0; i < 4; ++i) af[i]  = *(const bf16x8*)&As[wm + i * 16 + ln][quad * 8];
#pragma unroll
    for (int j = 0; j < 4; ++j) bfr[j] = *(const bf16x8*)&Bs[wn + j * 16 + ln][quad * 8];
#pragma unroll
    for (int i = 0; i < 4; ++i)
#pragma unroll
      for (int j = 0; j < 4; ++j)
        acc[i][j] = __builtin_amdgcn_mfma_f32_16x16x32_bf16(af[i], bfr[j], acc[i][j], 0, 0, 0);
  }

  if constexpr (VSPLIT) {
    if (n0 >= 2048) {
      __shared__ u16 Cs[128][72];
#pragma unroll
      for (int c = 0; c < 2; ++c) {
        if ((wave >> 1) == c) {
#pragma unroll
          for (int i = 0; i < 4; ++i)
#pragma unroll
            for (int j = 0; j < 4; ++j)
#pragma unroll
              for (int r = 0; r < 4; ++r) {
                int pos = (i >> 1) * 32 + quad * 8 + (i & 1) * 4 + r;
                Cs[wn + j * 16 + ln][pos] = f2bf(acc[i][j][r]);
              }
        }
        __syncthreads();
        {
          int nl = tid >> 1, mseg = (tid & 1) * 32;
#pragma unroll
          for (int s2 = 0; s2 < 4; ++s2) {
            uint4 v4 = *(const uint4*)&Cs[nl][mseg + s2 * 8];
            *(uint4*)&C2[(size_t)(n0 - 2048 + nl) * 4096 + m0 + c * 64 + mseg + s2 * 8] = v4;
          }
        }
        __syncthreads();
      }
      return;
    }
  }

#pragma unroll
  for (int i = 0; i < 4; ++i)
#pragma unroll
    for (int j = 0; j < 4; ++j)
#pragma unroll
      for (int r = 0; r < 4; ++r) {
        int m = m0 + wm + i * 16 + quad * 4 + r;
        int n = n0 + wn + j * 16 + ln;
        if constexpr (COUT_F32)
          ((float*)C)[(size_t)m * ldc + n] = acc[i][j][r];
        else
          ((u16*)C)[(size_t)m * ldc + n] = f2bf(acc[i][j][r]);
      }
}

// ---------------------------------------------------------------------------
// Causal flash attention (MFMA), fixed-base softmax (linearly decomposable),
// transposed score path (S^T = K·Q^T, in-register P^T B-frag, O^T = V^T·P^T).
// Q-tile 128 (2 strips/wave), K-tile 64, register-prefetch double buffer.
// SPLIT: grid 1024 = 32 qt x 2 key-halves x 16 heads, LPT (heavy chunks
//   first); min-waves 3 (NOT 4: the 2-strip kernel needs ~150 unified
//   VGPR+AGPR; capping at 128 caused scratch spills - R12's 748 MB WRITE);
//   writes bf16 unnormalized O-partial + fp32 l-partial; combine2 finishes.
// !SPLIT: grid 512, full range, writes normalized y (R11 behavior).
// ---------------------------------------------------------------------------
struct StageRegs { uint4 k0, k1, v0, v1; };

__device__ __forceinline__ StageRegs attn_stage_load(
    const u16* __restrict__ qk, const u16* __restrict__ vT,
    int h, int kbase, int tid) {
  StageRegs s;
  {
    int key = tid >> 2, seg = (tid & 3) * 16;
    const u16* kp = qk + (size_t)(kbase + key) * 2048 + 1024 + h * 64 + seg;
    s.k0 = *(const uint4*)kp;
    s.k1 = *(const uint4*)(kp + 8);
  }
  {
    int kh = tid >> 7, d = (tid >> 1) & 63, sg = (tid & 1) * 16;
    const u16* vp = vT + (size_t)(h * 64 + d) * 4096 + kbase + kh * 32 + sg;
    s.v0 = *(const uint4*)vp;
    s.v1 = *(const uint4*)(vp + 8);
  }
  return s;
}

template<bool SPLIT>
__global__ __launch_bounds__(256, SPLIT ? 3 : 2) void attn_fwd(
    const u16* __restrict__ qk, const u16* __restrict__ vT,
    u16* __restrict__ out0, u16* __restrict__ out1,
    float* __restrict__ l0buf, float* __restrict__ l1buf)
{
  __shared__ u16 Ks[2][2][64][40];     // [buf][d-half][key][d%32] pad 40
  __shared__ u16 Vt[2][2][64][40];     // [buf][pi-key-half][d][pos%32]

  const int tid  = threadIdx.x;
  const int wave = tid >> 6, lane = tid & 63;
  const int quad = lane >> 4, ln = lane & 15;
  const int bx = blockIdx.x;
  int qt, h, ktb, kte;
  u16* oout; float* lout;
  if constexpr (SPLIT) {
    qt = 31 - (bx >> 5);               // heavy chunks (qt+1 iters) first
    int half = (bx >> 4) & 1;
    h = bx & 15;
    ktb = half ? (qt + 1) : 0;
    kte = half ? (2 * qt + 1) : qt;
    oout = half ? out1 : out0;
    lout = half ? l1buf : l0buf;
  } else {
    qt = (bx < 256) ? (31 - (bx >> 4)) : ((bx - 256) >> 4);
    h = bx & 15;
    ktb = 0; kte = 2 * qt + 1;
    oout = out0; lout = nullptr;
  }
  const float C1 = 0.18033688f;        // 0.125 * log2(e)

  const int sq0[2] = { qt * 128 + wave * 32, qt * 128 + wave * 32 + 16 };

  bf16x8 qa[2][2];
#pragma unroll
  for (int s = 0; s < 2; ++s) {
    const u16* qrow = qk + (size_t)(sq0[s] + ln) * 2048 + h * 64;
    qa[s][0] = *(const bf16x8*)(qrow + quad * 8);
    qa[s][1] = *(const bf16x8*)(qrow + 32 + quad * 8);
  }

  f32x4 o[2][4] = {};                  // O^T tiles: [strip][d-tile]; row=d, col=qrow
  float l_i[2] = {0.f, 0.f};           // per-lane partial l for qrow=ln

  StageRegs st = attn_stage_load(qk, vT, h, ktb * 64, tid);
  int b = 0;
  for (int kt = ktb; kt <= kte; ++kt, b ^= 1) {
    {
      int key = tid >> 2, seg = (tid & 3) * 16;
      int kh = seg >> 5, off = seg & 31;
      *(uint4*)&Ks[b][kh][key][off]     = st.k0;
      *(uint4*)&Ks[b][kh][key][off + 8] = st.k1;
      int vh = tid >> 7, d = (tid >> 1) & 63, sg = (tid & 1) * 16;
      *(uint4*)&Vt[b][vh][d][sg]     = st.v0;
      *(uint4*)&Vt[b][vh][d][sg + 8] = st.v1;
    }
    __syncthreads();
    if (kt < kte) st = attn_stage_load(qk, vT, h, (kt + 1) * 64, tid);

    bf16x8 kf[2][4], vb[2][4];
#pragma unroll
    for (int hf = 0; hf < 2; ++hf)
#pragma unroll
      for (int c = 0; c < 4; ++c) {
        kf[hf][c] = *(const bf16x8*)&Ks[b][hf][c * 16 + ln][quad * 8];
        vb[hf][c] = *(const bf16x8*)&Vt[b][hf][c * 16 + ln][quad * 8];
      }

    bool act[2];
#pragma unroll
    for (int s = 0; s < 2; ++s) act[s] = (kt * 64 <= sq0[s] + 15);

    bf16x8 pb[2][2];
#pragma unroll
    for (int s = 0; s < 2; ++s) {
      if (!act[s]) continue;           // wave-uniform
      f32x4 sv[4];
#pragma unroll
      for (int t = 0; t < 4; ++t) {
        f32x4 z = {0.f, 0.f, 0.f, 0.f};
        z = __builtin_amdgcn_mfma_f32_16x16x32_bf16(kf[0][t], qa[s][0], z, 0, 0, 0);
        z = __builtin_amdgcn_mfma_f32_16x16x32_bf16(kf[1][t], qa[s][1], z, 0, 0, 0);
        sv[t] = z;                     // row=key=t*16+quad*4+r, col=qrow=ln
      }
      float p[4][4];                   // [t][r]
      if (kt * 64 + 63 > sq0[s]) {
        const int qr = sq0[s] + ln;
#pragma unroll
        for (int t = 0; t < 4; ++t) {
          int keyb = kt * 64 + t * 16 + quad * 4;
#pragma unroll
          for (int r = 0; r < 4; ++r) {
            float arg = (keyb + r > qr) ? -200.0f : fmaf(sv[t][r], C1, -46.0f);
            p[t][r] = fexp2(arg);
          }
        }
      } else {
#pragma unroll
        for (int t = 0; t < 4; ++t)
#pragma unroll
          for (int r = 0; r < 4; ++r)
            p[t][r] = fexp2(fmaf(sv[t][r], C1, -46.0f));
      }
#pragma unroll
      for (int t = 0; t < 4; ++t)
        l_i[s] += (p[t][0] + p[t][1]) + (p[t][2] + p[t][3]);
#pragma unroll
      for (int H = 0; H < 2; ++H) {
        union { unsigned u[4]; bf16x8 v; } pk;
        pk.u[0] = pkbf(p[2 * H][0],     p[2 * H][1]);
        pk.u[1] = pkbf(p[2 * H][2],     p[2 * H][3]);
        pk.u[2] = pkbf(p[2 * H + 1][0], p[2 * H + 1][1]);
        pk.u[3] = pkbf(p[2 * H + 1][2], p[2 * H + 1][3]);
        pb[s][H] = pk.v;
      }
    }

#pragma unroll
    for (int s = 0; s < 2; ++s) {
      if (!act[s]) continue;
#pragma unroll
      for (int dt = 0; dt < 4; ++dt) {
        f32x4 z = o[s][dt];
        z = __builtin_amdgcn_mfma_f32_16x16x32_bf16(vb[0][dt], pb[s][0], z, 0, 0, 0);
        z = __builtin_amdgcn_mfma_f32_16x16x32_bf16(vb[1][dt], pb[s][1], z, 0, 0, 0);
        o[s][dt] = z;
      }
    }
  }

#pragma unroll
  for (int s = 0; s < 2; ++s) {
    l_i[s] += __shfl_xor(l_i[s], 16);
    l_i[s] += __shfl_xor(l_i[s], 32);
    int rowg = sq0[s] + ln;
    if constexpr (SPLIT) {
      // unnormalized bf16 partial + fp32 l partial (quad 0 stores l once)
#pragma unroll
      for (int dt = 0; dt < 4; ++dt)
#pragma unroll
        for (int r = 0; r < 4; ++r)
          oout[(size_t)rowg * 1024 + h * 64 + dt * 16 + quad * 4 + r] = f2bf(o[s][dt][r]);
      if (quad == 0) lout[rowg * 16 + h] = l_i[s];
    } else {
      float inv = 1.0f / l_i[s];
#pragma unroll
      for (int dt = 0; dt < 4; ++dt)
#pragma unroll
        for (int r = 0; r < 4; ++r)
          oout[(size_t)rowg * 1024 + h * 64 + dt * 16 + quad * 4 + r] = f2bf(o[s][dt][r] * inv);
    }
  }
}

extern "C" void kernel_launch(void* const* d_in, const int* in_sizes, int n_in,
                              void* d_out, int out_size, void* d_ws, size_t ws_size,
                              hipStream_t stream) {
  const float* x      = (const float*)d_in[0];   // [4096,1024] fp32
  const float* w_attn = (const float*)d_in[1];   // [3072,1024] fp32
  const float* w_proj = (const float*)d_in[2];   // [1024,1024] fp32

  char* ws = (char*)d_ws;
  u16* qk = (u16*)ws;                        // 16 MiB [4096][2048]
  u16* vT = (u16*)(ws + (16u << 20));        //  8 MiB [1024][4096] pi-permuted

  if (ws_size >= (size_t)(44u << 20)) {
    // Path A: key-split attention with partial combine. Peak 42.25 MiB.
    u16*   wpb = (u16*)(ws + (24u << 20));   //  2 MiB bf16 w_proj
    u16*   xb  = (u16*)(ws + (26u << 20));   //  8 MiB bf16 x       (dead after GEMM1)
    u16*   wab = (u16*)(ws + (34u << 20));   //  6 MiB bf16 w_attn  (dead after GEMM1)
    u16*   Op0 = (u16*)(ws + (26u << 20));   //  8 MiB bf16 O-partial half0 (overlays xb)
    u16*   Op1 = (u16*)(ws + (34u << 20));   //  8 MiB bf16 O-partial half1 (overlays wab + 2 MiB)
    float* l0  = (float*)(ws + (42u << 20));            // 256 KiB
    float* l1  = (float*)(ws + (42u << 20) + (256u << 10)); // 256 KiB
    u16*   y   = (u16*)ws;                   //  8 MiB, overlays qk (dead after attn)

    cvt3<<<4096, 256, 0, stream>>>(x, w_attn, w_proj, xb, wab, wpb);
    gemm_lds<false, true><<<dim3(24, 32), 256, 0, stream>>>(
        xb, wab, qk, vT, 4096, 3072, 1024, 2048);
    attn_fwd<true><<<dim3(1024), 256, 0, stream>>>(qk, vT, Op0, Op1, l0, l1);
    combine2<<<2048, 256, 0, stream>>>(Op0, Op1, l0, l1, y);
    gemm_t64<true><<<dim3(16, 64), 256, 0, stream>>>(
        y, wpb, d_out, 4096, 1024, 1024, 1024);
  } else if (ws_size >= (size_t)(40u << 20)) {
    // Path B: R11 behavior.
    u16* wpb = (u16*)(ws + (24u << 20));
    u16* xb  = (u16*)(ws + (26u << 20));
    u16* wab = (u16*)(ws + (34u << 20));
    u16* y   = (u16*)(ws + (26u << 20));

    cvt3<<<4096, 256, 0, stream>>>(x, w_attn, w_proj, xb, wab, wpb);
    gemm_lds<false, true><<<dim3(24, 32), 256, 0, stream>>>(
        xb, wab, qk, vT, 4096, 3072, 1024, 2048);
    attn_fwd<false><<<dim3(512), 256, 0, stream>>>(qk, vT, y, nullptr, nullptr, nullptr);
    gemm_t64<true><<<dim3(16, 64), 256, 0, stream>>>(
        y, wpb, d_out, 4096, 1024, 1024, 1024);
  } else {
    // Path C: fp32-staging fallback.
    u16* y = (u16*)(ws + (24u << 20));
    gemm_bt<true, true, false, true><<<dim3(24, 32), 256, 0, stream>>>(
        x, w_attn, qk, vT, 4096, 3072, 1024, 2048);
    attn_fwd<false><<<dim3(512), 256, 0, stream>>>(qk, vT, y, nullptr, nullptr, nullptr);
    gemm_bt<false, true, true, false><<<dim3(8, 32), 256, 0, stream>>>(
        y, w_proj, d_out, nullptr, 4096, 1024, 1024, 1024);
  }
}

// Round 14
// 197.197 us; speedup vs baseline: 2.3203x; 1.2776x over previous
//
#include <hip/hip_runtime.h>

typedef unsigned short u16;
typedef __bf16 bf16x8 __attribute__((ext_vector_type(8)));
typedef float f32x4 __attribute__((ext_vector_type(4)));

// fp32 -> bf16 bits, round-to-nearest-even (finite inputs only)
__device__ __forceinline__ u16 f2bf(float f) {
  union { float f; unsigned u; } v; v.f = f;
  return (u16)((v.u + 0x7fffu + ((v.u >> 16) & 1u)) >> 16);
}
__device__ __forceinline__ float bf2f(u16 h) {
  union { unsigned u; float f; } v; v.u = ((unsigned)h) << 16;
  return v.f;
}

// pack two fp32 -> bf16x2 dword (round-half-up), low = lo, high = hi
__device__ __forceinline__ unsigned pkbf(float lo, float hi) {
  union { float f; unsigned u; } a, b; a.f = lo; b.f = hi;
  return __builtin_amdgcn_perm(b.u + 0x8000u, a.u + 0x8000u, 0x07060302u);
}

__device__ __forceinline__ float fexp2(float x) {
#if __has_builtin(__builtin_amdgcn_exp2f)
  return __builtin_amdgcn_exp2f(x);
#else
  return exp2f(x);
#endif
}

// async global->LDS, 16B per lane; LDS dst = base + lane*16 (wave-uniform base)
__device__ __forceinline__ void gld16(const u16* g, u16* l) {
  __builtin_amdgcn_global_load_lds(
      (const __attribute__((address_space(1))) void*)g,
      (__attribute__((address_space(3))) void*)l, 16, 0, 0);
}

// pi permutation of a key k in [0,64) -> position in vT 64-block / P^T k-slot:
// pos = (k&32) + ((k>>2)&3)*8 + ((k>>4)&1)*4 + (k&3)

// ---------------------------------------------------------------------------
// fp32 -> bf16 bulk convert for all three inputs in ONE dispatch.
// ---------------------------------------------------------------------------
__global__ __launch_bounds__(256) void cvt3(
    const float* __restrict__ x, const float* __restrict__ wa,
    const float* __restrict__ wp, u16* __restrict__ xb,
    u16* __restrict__ wab, u16* __restrict__ wpb)
{
  int b = blockIdx.x;
  const float* in; u16* out; int i;
  if (b < 2048)      { in = x;  out = xb;  i = b * 256 + threadIdx.x; }
  else if (b < 3584) { in = wa; out = wab; i = (b - 2048) * 256 + threadIdx.x; }
  else               { in = wp; out = wpb; i = (b - 3584) * 256 + threadIdx.x; }
  const float* p = in + (size_t)i * 8;
  float4 a = *(const float4*)p, c = *(const float4*)(p + 4);
  uint4 o;
  o.x = pkbf(a.x, a.y); o.y = pkbf(a.z, a.w);
  o.z = pkbf(c.x, c.y); o.w = pkbf(c.z, c.w);
  *(uint4*)&out[(size_t)i * 8] = o;
}

// ---------------------------------------------------------------------------
// combine: y = (O0 + O1) / (l0 + l1).  O* are bf16 unnormalized partials
// [4096][1024]; l* are fp32 [4096][16] (per row,head). 8 elems/thread.
// ---------------------------------------------------------------------------
__global__ __launch_bounds__(256) void combine2(
    const u16* __restrict__ O0, const u16* __restrict__ O1,
    const float* __restrict__ l0, const float* __restrict__ l1,
    u16* __restrict__ y)
{
  int i = blockIdx.x * 256 + threadIdx.x;          // 524288 threads
  int e0 = i * 8;
  int row = e0 >> 10, h = (e0 & 1023) >> 6;
  float inv = 1.0f / (l0[row * 16 + h] + l1[row * 16 + h]);
  uint4 a = *(const uint4*)&O0[(size_t)e0];
  uint4 b = *(const uint4*)&O1[(size_t)e0];
  unsigned aw[4] = {a.x, a.y, a.z, a.w}, bw[4] = {b.x, b.y, b.z, b.w};
  uint4 o;
  unsigned ow[4];
#pragma unroll
  for (int j = 0; j < 4; ++j) {
    float lo = (bf2f((u16)(aw[j] & 0xffffu)) + bf2f((u16)(bw[j] & 0xffffu))) * inv;
    float hi = (bf2f((u16)(aw[j] >> 16))     + bf2f((u16)(bw[j] >> 16)))     * inv;
    ow[j] = pkbf(lo, hi);
  }
  o.x = ow[0]; o.y = ow[1]; o.z = ow[2]; o.w = ow[3];
  *(uint4*)&y[(size_t)e0] = o;
}

// ---------------------------------------------------------------------------
// m97-style GEMM: C[M,N] = A[M,K]*B[N,K]^T, bf16 in, fp32 acc.
// VSPLIT: n0>=2048 blocks write V TRANSPOSED to C2 (vT[1024][4096]) in
// pi-permuted key order.
// ---------------------------------------------------------------------------
template<bool COUT_F32, bool VSPLIT>
__global__ __launch_bounds__(256, 3) void gemm_lds(
    const u16* __restrict__ A, const u16* __restrict__ B, void* __restrict__ C,
    u16* __restrict__ C2, int M, int N, int K, int ldc)
{
  __shared__ u16 S[9216];
  u16* As = S;
  u16* Bs = S + 4096;
  const int tid  = threadIdx.x;
  const int wave = tid >> 6, lane = tid & 63;
  const int quad = lane >> 4, ln = lane & 15;
  const int m0 = blockIdx.y * 128, n0 = blockIdx.x * 128;
  const int wm = (wave >> 1) * 64, wn = (wave & 1) * 64;

  const int srow = wave * 32 + (lane >> 2);
  const int scol = (lane & 3) * 8;

  f32x4 acc[4][4] = {};

  for (int k0 = 0; k0 < K; k0 += 32) {
    __syncthreads();
    const u16* ga = A + (size_t)(m0 + srow) * K + k0 + scol;
    const u16* gb = B + (size_t)(n0 + srow) * K + k0 + scol;
    gld16(ga,                  As + wave * 1024);
    gld16(ga + (size_t)16 * K, As + wave * 1024 + 512);
    gld16(gb,                  Bs + wave * 1024);
    gld16(gb + (size_t)16 * K, Bs + wave * 1024 + 512);
    __syncthreads();

    bf16x8 af[4], bfr[4];
#pragma unroll
    for (int i = 0; i < 4; ++i) af[i]  = *(const bf16x8*)&As[(wm + i * 16 + ln) * 32 + quad * 8];
#pragma unroll
    for (int j = 0; j < 4; ++j) bfr[j] = *(const bf16x8*)&Bs[(wn + j * 16 + ln) * 32 + quad * 8];
#pragma unroll
    for (int i = 0; i < 4; ++i)
#pragma unroll
      for (int j = 0; j < 4; ++j)
        acc[i][j] = __builtin_amdgcn_mfma_f32_16x16x32_bf16(af[i], bfr[j], acc[i][j], 0, 0, 0);
  }

  if constexpr (VSPLIT) {
    if (n0 >= 2048) {
      u16 (*Cs)[72] = (u16(*)[72])S;
      __syncthreads();
#pragma unroll
      for (int c = 0; c < 2; ++c) {
        if ((wave >> 1) == c) {
#pragma unroll
          for (int i = 0; i < 4; ++i)
#pragma unroll
            for (int j = 0; j < 4; ++j)
#pragma unroll
              for (int r = 0; r < 4; ++r) {
                int pos = (i >> 1) * 32 + quad * 8 + (i & 1) * 4 + r;  // pi(m-in-chunk)
                Cs[wn + j * 16 + ln][pos] = f2bf(acc[i][j][r]);
              }
        }
        __syncthreads();
        {
          int nl = tid >> 1, mseg = (tid & 1) * 32;
#pragma unroll
          for (int s2 = 0; s2 < 4; ++s2) {
            uint4 v4 = *(const uint4*)&Cs[nl][mseg + s2 * 8];
            *(uint4*)&C2[(size_t)(n0 - 2048 + nl) * 4096 + m0 + c * 64 + mseg + s2 * 8] = v4;
          }
        }
        __syncthreads();
      }
      return;
    }
  }

#pragma unroll
  for (int i = 0; i < 4; ++i)
#pragma unroll
    for (int j = 0; j < 4; ++j)
#pragma unroll
      for (int r = 0; r < 4; ++r) {
        int m = m0 + wm + i * 16 + quad * 4 + r;   // C/D: row = quad*4+reg
        int n = n0 + wn + j * 16 + ln;             //      col = lane&15
        if constexpr (COUT_F32)
          ((float*)C)[(size_t)m * ldc + n] = acc[i][j][r];
        else
          ((u16*)C)[(size_t)m * ldc + n] = f2bf(acc[i][j][r]);
      }
}

// ---------------------------------------------------------------------------
// 64x64-tile GEMM for GEMM2 (latency-bound -> 4 blocks/CU).
// ---------------------------------------------------------------------------
template<bool COUT_F32>
__global__ __launch_bounds__(256, 4) void gemm_t64(
    const u16* __restrict__ A, const u16* __restrict__ B, void* __restrict__ C,
    int M, int N, int K, int ldc)
{
  __shared__ u16 S[4096];            // As[64][32]@0, Bs[64][32]@2048
  u16* As = S;
  u16* Bs = S + 2048;
  const int tid  = threadIdx.x;
  const int wave = tid >> 6, lane = tid & 63;
  const int quad = lane >> 4, ln = lane & 15;
  const int m0 = blockIdx.y * 64, n0 = blockIdx.x * 64;

  const int srow = wave * 16 + (lane >> 2);
  const int scol = (lane & 3) * 8;

  f32x4 acc[4] = {};

  for (int k0 = 0; k0 < K; k0 += 32) {
    __syncthreads();
    gld16(A + (size_t)(m0 + srow) * K + k0 + scol, As + wave * 512);
    gld16(B + (size_t)(n0 + srow) * K + k0 + scol, Bs + wave * 512);
    __syncthreads();

    bf16x8 af = *(const bf16x8*)&As[(wave * 16 + ln) * 32 + quad * 8];
#pragma unroll
    for (int j = 0; j < 4; ++j) {
      bf16x8 bf = *(const bf16x8*)&Bs[(j * 16 + ln) * 32 + quad * 8];
      acc[j] = __builtin_amdgcn_mfma_f32_16x16x32_bf16(af, bf, acc[j], 0, 0, 0);
    }
  }

#pragma unroll
  for (int j = 0; j < 4; ++j)
#pragma unroll
    for (int r = 0; r < 4; ++r) {
      int m = m0 + wave * 16 + quad * 4 + r;
      int n = n0 + j * 16 + ln;
      if constexpr (COUT_F32)
        ((float*)C)[(size_t)m * ldc + n] = acc[j][r];
      else
        ((u16*)C)[(size_t)m * ldc + n] = f2bf(acc[j][r]);
    }
}

// ---------------------------------------------------------------------------
// Fallback GEMM (fp32 staging) — used only if ws_size < 40 MiB.
// ---------------------------------------------------------------------------
template<bool F32>
__device__ __forceinline__ void stage8(u16* dst, const void* base, size_t off) {
  if constexpr (F32) {
    const float* p = (const float*)base + off;
    float4 a = *(const float4*)p;
    float4 b = *(const float4*)(p + 4);
    uint4 q;
    q.x = pkbf(a.x, a.y); q.y = pkbf(a.z, a.w);
    q.z = pkbf(b.x, b.y); q.w = pkbf(b.z, b.w);
    *(uint4*)dst = q;
  } else {
    *(uint4*)dst = *(const uint4*)((const u16*)base + off);
  }
}

template<bool AF32, bool BF32, bool COUT_F32, bool VSPLIT>
__global__ __launch_bounds__(256) void gemm_bt(
    const void* __restrict__ A, const void* __restrict__ B, void* __restrict__ C,
    u16* __restrict__ C2, int M, int N, int K, int ldc)
{
  __shared__ u16 As[128][40];
  __shared__ u16 Bs[128][40];
  const int tid  = threadIdx.x;
  const int wave = tid >> 6, lane = tid & 63;
  const int quad = lane >> 4, ln = lane & 15;
  const int m0 = blockIdx.y * 128, n0 = blockIdx.x * 128;
  const int wm = (wave >> 1) * 64, wn = (wave & 1) * 64;

  f32x4 acc[4][4] = {};

  for (int k0 = 0; k0 < K; k0 += 32) {
    __syncthreads();
#pragma unroll
    for (int i = 0; i < 2; ++i) {
      int idx = tid + i * 256;
      int row = idx >> 2, seg = (idx & 3) * 8;
      stage8<AF32>(&As[row][seg], A, (size_t)(m0 + row) * K + k0 + seg);
      stage8<BF32>(&Bs[row][seg], B, (size_t)(n0 + row) * K + k0 + seg);
    }
    __syncthreads();
    bf16x8 af[4], bfr[4];
#pragma unroll
    for (int i = 0; i < 4; ++i) af[i]  = *(const bf16x8*)&As[wm + i * 16 + ln][quad * 8];
#pragma unroll
    for (int j = 0; j < 4; ++j) bfr[j] = *(const bf16x8*)&Bs[wn + j * 16 + ln][quad * 8];
#pragma unroll
    for (int i = 0; i < 4; ++i)
#pragma unroll
      for (int j = 0; j < 4; ++j)
        acc[i][j] = __builtin_amdgcn_mfma_f32_16x16x32_bf16(af[i], bfr[j], acc[i][j], 0, 0, 0);
  }

  if constexpr (VSPLIT) {
    if (n0 >= 2048) {
      __shared__ u16 Cs[128][72];
#pragma unroll
      for (int c = 0; c < 2; ++c) {
        if ((wave >> 1) == c) {
#pragma unroll
          for (int i = 0; i < 4; ++i)
#pragma unroll
            for (int j = 0; j < 4; ++j)
#pragma unroll
              for (int r = 0; r < 4; ++r) {
                int pos = (i >> 1) * 32 + quad * 8 + (i & 1) * 4 + r;
                Cs[wn + j * 16 + ln][pos] = f2bf(acc[i][j][r]);
              }
        }
        __syncthreads();
        {
          int nl = tid >> 1, mseg = (tid & 1) * 32;
#pragma unroll
          for (int s2 = 0; s2 < 4; ++s2) {
            uint4 v4 = *(const uint4*)&Cs[nl][mseg + s2 * 8];
            *(uint4*)&C2[(size_t)(n0 - 2048 + nl) * 4096 + m0 + c * 64 + mseg + s2 * 8] = v4;
          }
        }
        __syncthreads();
      }
      return;
    }
  }

#pragma unroll
  for (int i = 0; i < 4; ++i)
#pragma unroll
    for (int j = 0; j < 4; ++j)
#pragma unroll
      for (int r = 0; r < 4; ++r) {
        int m = m0 + wm + i * 16 + quad * 4 + r;
        int n = n0 + wn + j * 16 + ln;
        if constexpr (COUT_F32)
          ((float*)C)[(size_t)m * ldc + n] = acc[i][j][r];
        else
          ((u16*)C)[(size_t)m * ldc + n] = f2bf(acc[i][j][r]);
      }
}

// ---------------------------------------------------------------------------
// Causal flash attention (MFMA), fixed-base softmax (linearly decomposable),
// transposed score path (S^T = K·Q^T, in-register P^T B-frag, O^T = V^T·P^T).
// Q-tile 128 (2 strips/wave), K-tile 64, register-prefetch double buffer.
// Register need ~200 unified VGPR+AGPR (calibrated R11/R12/R13: cap 256 ->
// clean, cap 170 -> 145 MB spill, cap 128 -> 748 MB spill) => min-waves MUST
// be 2. The split's win comes from grid 1024 > 512 slots: slots REFILL,
// LPT order (chunk sizes 1..32 iters, heavy first) balances the makespan.
// SPLIT: half0 kt in [0,qt], half1 kt in [qt+1,2qt+1]; writes bf16
// unnormalized O-partial + fp32 l-partial; combine2 finishes.
// !SPLIT: grid 512, full range, writes normalized y (R11 behavior).
// ---------------------------------------------------------------------------
struct StageRegs { uint4 k0, k1, v0, v1; };

__device__ __forceinline__ StageRegs attn_stage_load(
    const u16* __restrict__ qk, const u16* __restrict__ vT,
    int h, int kbase, int tid) {
  StageRegs s;
  {
    int key = tid >> 2, seg = (tid & 3) * 16;
    const u16* kp = qk + (size_t)(kbase + key) * 2048 + 1024 + h * 64 + seg;
    s.k0 = *(const uint4*)kp;
    s.k1 = *(const uint4*)(kp + 8);
  }
  {
    int kh = tid >> 7, d = (tid >> 1) & 63, sg = (tid & 1) * 16;
    const u16* vp = vT + (size_t)(h * 64 + d) * 4096 + kbase + kh * 32 + sg;
    s.v0 = *(const uint4*)vp;
    s.v1 = *(const uint4*)(vp + 8);
  }
  return s;
}

template<bool SPLIT>
__global__ __launch_bounds__(256, 2) void attn_fwd(
    const u16* __restrict__ qk, const u16* __restrict__ vT,
    u16* __restrict__ out0, u16* __restrict__ out1,
    float* __restrict__ l0buf, float* __restrict__ l1buf)
{
  __shared__ u16 Ks[2][2][64][40];     // [buf][d-half][key][d%32] pad 40
  __shared__ u16 Vt[2][2][64][40];     // [buf][pi-key-half][d][pos%32]

  const int tid  = threadIdx.x;
  const int wave = tid >> 6, lane = tid & 63;
  const int quad = lane >> 4, ln = lane & 15;
  const int bx = blockIdx.x;
  int qt, h, ktb, kte;
  u16* oout; float* lout;
  if constexpr (SPLIT) {
    qt = 31 - (bx >> 5);               // heavy chunks (qt+1 iters) first
    int half = (bx >> 4) & 1;
    h = bx & 15;
    ktb = half ? (qt + 1) : 0;
    kte = half ? (2 * qt + 1) : qt;
    oout = half ? out1 : out0;
    lout = half ? l1buf : l0buf;
  } else {
    qt = (bx < 256) ? (31 - (bx >> 4)) : ((bx - 256) >> 4);
    h = bx & 15;
    ktb = 0; kte = 2 * qt + 1;
    oout = out0; lout = nullptr;
  }
  const float C1 = 0.18033688f;        // 0.125 * log2(e)

  const int sq0[2] = { qt * 128 + wave * 32, qt * 128 + wave * 32 + 16 };

  bf16x8 qa[2][2];
#pragma unroll
  for (int s = 0; s < 2; ++s) {
    const u16* qrow = qk + (size_t)(sq0[s] + ln) * 2048 + h * 64;
    qa[s][0] = *(const bf16x8*)(qrow + quad * 8);
    qa[s][1] = *(const bf16x8*)(qrow + 32 + quad * 8);
  }

  f32x4 o[2][4] = {};                  // O^T tiles: [strip][d-tile]; row=d, col=qrow
  float l_i[2] = {0.f, 0.f};           // per-lane partial l for qrow=ln

  StageRegs st = attn_stage_load(qk, vT, h, ktb * 64, tid);
  int b = 0;
  for (int kt = ktb; kt <= kte; ++kt, b ^= 1) {
    {
      int key = tid >> 2, seg = (tid & 3) * 16;
      int kh = seg >> 5, off = seg & 31;
      *(uint4*)&Ks[b][kh][key][off]     = st.k0;
      *(uint4*)&Ks[b][kh][key][off + 8] = st.k1;
      int vh = tid >> 7, d = (tid >> 1) & 63, sg = (tid & 1) * 16;
      *(uint4*)&Vt[b][vh][d][sg]     = st.v0;
      *(uint4*)&Vt[b][vh][d][sg + 8] = st.v1;
    }
    __syncthreads();
    if (kt < kte) st = attn_stage_load(qk, vT, h, (kt + 1) * 64, tid);

    bf16x8 kf[2][4], vb[2][4];
#pragma unroll
    for (int hf = 0; hf < 2; ++hf)
#pragma unroll
      for (int c = 0; c < 4; ++c) {
        kf[hf][c] = *(const bf16x8*)&Ks[b][hf][c * 16 + ln][quad * 8];
        vb[hf][c] = *(const bf16x8*)&Vt[b][hf][c * 16 + ln][quad * 8];
      }

    bool act[2];
#pragma unroll
    for (int s = 0; s < 2; ++s) act[s] = (kt * 64 <= sq0[s] + 15);

    bf16x8 pb[2][2];
#pragma unroll
    for (int s = 0; s < 2; ++s) {
      if (!act[s]) continue;           // wave-uniform
      f32x4 sv[4];
#pragma unroll
      for (int t = 0; t < 4; ++t) {
        f32x4 z = {0.f, 0.f, 0.f, 0.f};
        z = __builtin_amdgcn_mfma_f32_16x16x32_bf16(kf[0][t], qa[s][0], z, 0, 0, 0);
        z = __builtin_amdgcn_mfma_f32_16x16x32_bf16(kf[1][t], qa[s][1], z, 0, 0, 0);
        sv[t] = z;                     // row=key=t*16+quad*4+r, col=qrow=ln
      }
      float p[4][4];                   // [t][r]
      if (kt * 64 + 63 > sq0[s]) {
        const int qr = sq0[s] + ln;
#pragma unroll
        for (int t = 0; t < 4; ++t) {
          int keyb = kt * 64 + t * 16 + quad * 4;
#pragma unroll
          for (int r = 0; r < 4; ++r) {
            float arg = (keyb + r > qr) ? -200.0f : fmaf(sv[t][r], C1, -46.0f);
            p[t][r] = fexp2(arg);
          }
        }
      } else {
#pragma unroll
        for (int t = 0; t < 4; ++t)
#pragma unroll
          for (int r = 0; r < 4; ++r)
            p[t][r] = fexp2(fmaf(sv[t][r], C1, -46.0f));
      }
#pragma unroll
      for (int t = 0; t < 4; ++t)
        l_i[s] += (p[t][0] + p[t][1]) + (p[t][2] + p[t][3]);
#pragma unroll
      for (int H = 0; H < 2; ++H) {
        union { unsigned u[4]; bf16x8 v; } pk;
        pk.u[0] = pkbf(p[2 * H][0],     p[2 * H][1]);
        pk.u[1] = pkbf(p[2 * H][2],     p[2 * H][3]);
        pk.u[2] = pkbf(p[2 * H + 1][0], p[2 * H + 1][1]);
        pk.u[3] = pkbf(p[2 * H + 1][2], p[2 * H + 1][3]);
        pb[s][H] = pk.v;
      }
    }

#pragma unroll
    for (int s = 0; s < 2; ++s) {
      if (!act[s]) continue;
#pragma unroll
      for (int dt = 0; dt < 4; ++dt) {
        f32x4 z = o[s][dt];
        z = __builtin_amdgcn_mfma_f32_16x16x32_bf16(vb[0][dt], pb[s][0], z, 0, 0, 0);
        z = __builtin_amdgcn_mfma_f32_16x16x32_bf16(vb[1][dt], pb[s][1], z, 0, 0, 0);
        o[s][dt] = z;
      }
    }
  }

#pragma unroll
  for (int s = 0; s < 2; ++s) {
    l_i[s] += __shfl_xor(l_i[s], 16);
    l_i[s] += __shfl_xor(l_i[s], 32);
    int rowg = sq0[s] + ln;
    if constexpr (SPLIT) {
      // unnormalized bf16 partial + fp32 l partial (quad 0 stores l once)
#pragma unroll
      for (int dt = 0; dt < 4; ++dt)
#pragma unroll
        for (int r = 0; r < 4; ++r)
          oout[(size_t)rowg * 1024 + h * 64 + dt * 16 + quad * 4 + r] = f2bf(o[s][dt][r]);
      if (quad == 0) lout[rowg * 16 + h] = l_i[s];
    } else {
      float inv = 1.0f / l_i[s];
#pragma unroll
      for (int dt = 0; dt < 4; ++dt)
#pragma unroll
        for (int r = 0; r < 4; ++r)
          oout[(size_t)rowg * 1024 + h * 64 + dt * 16 + quad * 4 + r] = f2bf(o[s][dt][r] * inv);
    }
  }
}

extern "C" void kernel_launch(void* const* d_in, const int* in_sizes, int n_in,
                              void* d_out, int out_size, void* d_ws, size_t ws_size,
                              hipStream_t stream) {
  const float* x      = (const float*)d_in[0];   // [4096,1024] fp32
  const float* w_attn = (const float*)d_in[1];   // [3072,1024] fp32
  const float* w_proj = (const float*)d_in[2];   // [1024,1024] fp32

  char* ws = (char*)d_ws;
  u16* qk = (u16*)ws;                        // 16 MiB [4096][2048]
  u16* vT = (u16*)(ws + (16u << 20));        //  8 MiB [1024][4096] pi-permuted

  if (ws_size >= (size_t)(44u << 20)) {
    // Path A: key-split attention with partial combine. Peak 42.25 MiB.
    u16*   wpb = (u16*)(ws + (24u << 20));   //  2 MiB bf16 w_proj
    u16*   xb  = (u16*)(ws + (26u << 20));   //  8 MiB bf16 x       (dead after GEMM1)
    u16*   wab = (u16*)(ws + (34u << 20));   //  6 MiB bf16 w_attn  (dead after GEMM1)
    u16*   Op0 = (u16*)(ws + (26u << 20));   //  8 MiB bf16 O-partial half0 (overlays xb)
    u16*   Op1 = (u16*)(ws + (34u << 20));   //  8 MiB bf16 O-partial half1 (overlays wab + 2 MiB)
    float* l0  = (float*)(ws + (42u << 20));            // 256 KiB
    float* l1  = (float*)(ws + (42u << 20) + (256u << 10)); // 256 KiB
    u16*   y   = (u16*)ws;                   //  8 MiB, overlays qk (dead after attn)

    cvt3<<<4096, 256, 0, stream>>>(x, w_attn, w_proj, xb, wab, wpb);
    gemm_lds<false, true><<<dim3(24, 32), 256, 0, stream>>>(
        xb, wab, qk, vT, 4096, 3072, 1024, 2048);
    attn_fwd<true><<<dim3(1024), 256, 0, stream>>>(qk, vT, Op0, Op1, l0, l1);
    combine2<<<2048, 256, 0, stream>>>(Op0, Op1, l0, l1, y);
    gemm_t64<true><<<dim3(16, 64), 256, 0, stream>>>(
        y, wpb, d_out, 4096, 1024, 1024, 1024);
  } else if (ws_size >= (size_t)(40u << 20)) {
    // Path B: R11 behavior.
    u16* wpb = (u16*)(ws + (24u << 20));
    u16* xb  = (u16*)(ws + (26u << 20));
    u16* wab = (u16*)(ws + (34u << 20));
    u16* y   = (u16*)(ws + (26u << 20));

    cvt3<<<4096, 256, 0, stream>>>(x, w_attn, w_proj, xb, wab, wpb);
    gemm_lds<false, true><<<dim3(24, 32), 256, 0, stream>>>(
        xb, wab, qk, vT, 4096, 3072, 1024, 2048);
    attn_fwd<false><<<dim3(512), 256, 0, stream>>>(qk, vT, y, nullptr, nullptr, nullptr);
    gemm_t64<true><<<dim3(16, 64), 256, 0, stream>>>(
        y, wpb, d_out, 4096, 1024, 1024, 1024);
  } else {
    // Path C: fp32-staging fallback.
    u16* y = (u16*)(ws + (24u << 20));
    gemm_bt<true, true, false, true><<<dim3(24, 32), 256, 0, stream>>>(
        x, w_attn, qk, vT, 4096, 3072, 1024, 2048);
    attn_fwd<false><<<dim3(512), 256, 0, stream>>>(qk, vT, y, nullptr, nullptr, nullptr);
    gemm_bt<false, true, true, false><<<dim3(8, 32), 256, 0, stream>>>(
        y, w_proj, d_out, nullptr, 4096, 1024, 1024, 1024);
  }
}

// Round 15
// 188.400 us; speedup vs baseline: 2.4287x; 1.0467x over previous
//
#include <hip/hip_runtime.h>

typedef unsigned short u16;
typedef __bf16 bf16x8 __attribute__((ext_vector_type(8)));
typedef float f32x4 __attribute__((ext_vector_type(4)));

// fp32 -> bf16 bits, round-to-nearest-even (finite inputs only)
__device__ __forceinline__ u16 f2bf(float f) {
  union { float f; unsigned u; } v; v.f = f;
  return (u16)((v.u + 0x7fffu + ((v.u >> 16) & 1u)) >> 16);
}
__device__ __forceinline__ float bf2f(u16 h) {
  union { unsigned u; float f; } v; v.u = ((unsigned)h) << 16;
  return v.f;
}

// pack two fp32 -> bf16x2 dword (round-half-up), low = lo, high = hi
__device__ __forceinline__ unsigned pkbf(float lo, float hi) {
  union { float f; unsigned u; } a, b; a.f = lo; b.f = hi;
  return __builtin_amdgcn_perm(b.u + 0x8000u, a.u + 0x8000u, 0x07060302u);
}

__device__ __forceinline__ float fexp2(float x) {
#if __has_builtin(__builtin_amdgcn_exp2f)
  return __builtin_amdgcn_exp2f(x);
#else
  return exp2f(x);
#endif
}

// async global->LDS, 16B per lane; LDS dst = base + lane*16 (wave-uniform base)
__device__ __forceinline__ void gld16(const u16* g, u16* l) {
  __builtin_amdgcn_global_load_lds(
      (const __attribute__((address_space(1))) void*)g,
      (__attribute__((address_space(3))) void*)l, 16, 0, 0);
}

// pi permutation of a key k in [0,64) -> position in vT 64-block / P^T k-slot:
// pos = (k&32) + ((k>>2)&3)*8 + ((k>>4)&1)*4 + (k&3)

// ---------------------------------------------------------------------------
// fp32 -> bf16 bulk convert for all three inputs in ONE dispatch.
// ---------------------------------------------------------------------------
__global__ __launch_bounds__(256) void cvt3(
    const float* __restrict__ x, const float* __restrict__ wa,
    const float* __restrict__ wp, u16* __restrict__ xb,
    u16* __restrict__ wab, u16* __restrict__ wpb)
{
  int b = blockIdx.x;
  const float* in; u16* out; int i;
  if (b < 2048)      { in = x;  out = xb;  i = b * 256 + threadIdx.x; }
  else if (b < 3584) { in = wa; out = wab; i = (b - 2048) * 256 + threadIdx.x; }
  else               { in = wp; out = wpb; i = (b - 3584) * 256 + threadIdx.x; }
  const float* p = in + (size_t)i * 8;
  float4 a = *(const float4*)p, c = *(const float4*)(p + 4);
  uint4 o;
  o.x = pkbf(a.x, a.y); o.y = pkbf(a.z, a.w);
  o.z = pkbf(c.x, c.y); o.w = pkbf(c.z, c.w);
  *(uint4*)&out[(size_t)i * 8] = o;
}

// ---------------------------------------------------------------------------
// combine: y = (O0 + O1) / (l0 + l1).  O* are bf16 unnormalized partials
// [4096][1024]; l* are fp32 [4096][16] (per row,head). 8 elems/thread.
// ---------------------------------------------------------------------------
__global__ __launch_bounds__(256) void combine2(
    const u16* __restrict__ O0, const u16* __restrict__ O1,
    const float* __restrict__ l0, const float* __restrict__ l1,
    u16* __restrict__ y)
{
  int i = blockIdx.x * 256 + threadIdx.x;          // 524288 threads
  int e0 = i * 8;
  int row = e0 >> 10, h = (e0 & 1023) >> 6;
  float inv = 1.0f / (l0[row * 16 + h] + l1[row * 16 + h]);
  uint4 a = *(const uint4*)&O0[(size_t)e0];
  uint4 b = *(const uint4*)&O1[(size_t)e0];
  unsigned aw[4] = {a.x, a.y, a.z, a.w}, bw[4] = {b.x, b.y, b.z, b.w};
  uint4 o;
  unsigned ow[4];
#pragma unroll
  for (int j = 0; j < 4; ++j) {
    float lo = (bf2f((u16)(aw[j] & 0xffffu)) + bf2f((u16)(bw[j] & 0xffffu))) * inv;
    float hi = (bf2f((u16)(aw[j] >> 16))     + bf2f((u16)(bw[j] >> 16)))     * inv;
    ow[j] = pkbf(lo, hi);
  }
  o.x = ow[0]; o.y = ow[1]; o.z = ow[2]; o.w = ow[3];
  *(uint4*)&y[(size_t)e0] = o;
}

// ---------------------------------------------------------------------------
// m97-style GEMM: C[M,N] = A[M,K]*B[N,K]^T, bf16 in, fp32 acc.
// VSPLIT: n0>=2048 blocks write V TRANSPOSED to C2 (vT[1024][4096]) in
// pi-permuted key order.
// ---------------------------------------------------------------------------
template<bool COUT_F32, bool VSPLIT>
__global__ __launch_bounds__(256, 3) void gemm_lds(
    const u16* __restrict__ A, const u16* __restrict__ B, void* __restrict__ C,
    u16* __restrict__ C2, int M, int N, int K, int ldc)
{
  __shared__ u16 S[9216];
  u16* As = S;
  u16* Bs = S + 4096;
  const int tid  = threadIdx.x;
  const int wave = tid >> 6, lane = tid & 63;
  const int quad = lane >> 4, ln = lane & 15;
  const int m0 = blockIdx.y * 128, n0 = blockIdx.x * 128;
  const int wm = (wave >> 1) * 64, wn = (wave & 1) * 64;

  const int srow = wave * 32 + (lane >> 2);
  const int scol = (lane & 3) * 8;

  f32x4 acc[4][4] = {};

  for (int k0 = 0; k0 < K; k0 += 32) {
    __syncthreads();
    const u16* ga = A + (size_t)(m0 + srow) * K + k0 + scol;
    const u16* gb = B + (size_t)(n0 + srow) * K + k0 + scol;
    gld16(ga,                  As + wave * 1024);
    gld16(ga + (size_t)16 * K, As + wave * 1024 + 512);
    gld16(gb,                  Bs + wave * 1024);
    gld16(gb + (size_t)16 * K, Bs + wave * 1024 + 512);
    __syncthreads();

    bf16x8 af[4], bfr[4];
#pragma unroll
    for (int i = 0; i < 4; ++i) af[i]  = *(const bf16x8*)&As[(wm + i * 16 + ln) * 32 + quad * 8];
#pragma unroll
    for (int j = 0; j < 4; ++j) bfr[j] = *(const bf16x8*)&Bs[(wn + j * 16 + ln) * 32 + quad * 8];
#pragma unroll
    for (int i = 0; i < 4; ++i)
#pragma unroll
      for (int j = 0; j < 4; ++j)
        acc[i][j] = __builtin_amdgcn_mfma_f32_16x16x32_bf16(af[i], bfr[j], acc[i][j], 0, 0, 0);
  }

  if constexpr (VSPLIT) {
    if (n0 >= 2048) {
      u16 (*Cs)[72] = (u16(*)[72])S;
      __syncthreads();
#pragma unroll
      for (int c = 0; c < 2; ++c) {
        if ((wave >> 1) == c) {
#pragma unroll
          for (int i = 0; i < 4; ++i)
#pragma unroll
            for (int j = 0; j < 4; ++j)
#pragma unroll
              for (int r = 0; r < 4; ++r) {
                int pos = (i >> 1) * 32 + quad * 8 + (i & 1) * 4 + r;  // pi(m-in-chunk)
                Cs[wn + j * 16 + ln][pos] = f2bf(acc[i][j][r]);
              }
        }
        __syncthreads();
        {
          int nl = tid >> 1, mseg = (tid & 1) * 32;
#pragma unroll
          for (int s2 = 0; s2 < 4; ++s2) {
            uint4 v4 = *(const uint4*)&Cs[nl][mseg + s2 * 8];
            *(uint4*)&C2[(size_t)(n0 - 2048 + nl) * 4096 + m0 + c * 64 + mseg + s2 * 8] = v4;
          }
        }
        __syncthreads();
      }
      return;
    }
  }

#pragma unroll
  for (int i = 0; i < 4; ++i)
#pragma unroll
    for (int j = 0; j < 4; ++j)
#pragma unroll
      for (int r = 0; r < 4; ++r) {
        int m = m0 + wm + i * 16 + quad * 4 + r;   // C/D: row = quad*4+reg
        int n = n0 + wn + j * 16 + ln;             //      col = lane&15
        if constexpr (COUT_F32)
          ((float*)C)[(size_t)m * ldc + n] = acc[i][j][r];
        else
          ((u16*)C)[(size_t)m * ldc + n] = f2bf(acc[i][j][r]);
      }
}

// ---------------------------------------------------------------------------
// 64x64-tile GEMM for GEMM2 (latency-bound -> 4 blocks/CU).
// ---------------------------------------------------------------------------
template<bool COUT_F32>
__global__ __launch_bounds__(256, 4) void gemm_t64(
    const u16* __restrict__ A, const u16* __restrict__ B, void* __restrict__ C,
    int M, int N, int K, int ldc)
{
  __shared__ u16 S[4096];            // As[64][32]@0, Bs[64][32]@2048
  u16* As = S;
  u16* Bs = S + 2048;
  const int tid  = threadIdx.x;
  const int wave = tid >> 6, lane = tid & 63;
  const int quad = lane >> 4, ln = lane & 15;
  const int m0 = blockIdx.y * 64, n0 = blockIdx.x * 64;

  const int srow = wave * 16 + (lane >> 2);
  const int scol = (lane & 3) * 8;

  f32x4 acc[4] = {};

  for (int k0 = 0; k0 < K; k0 += 32) {
    __syncthreads();
    gld16(A + (size_t)(m0 + srow) * K + k0 + scol, As + wave * 512);
    gld16(B + (size_t)(n0 + srow) * K + k0 + scol, Bs + wave * 512);
    __syncthreads();

    bf16x8 af = *(const bf16x8*)&As[(wave * 16 + ln) * 32 + quad * 8];
#pragma unroll
    for (int j = 0; j < 4; ++j) {
      bf16x8 bf = *(const bf16x8*)&Bs[(j * 16 + ln) * 32 + quad * 8];
      acc[j] = __builtin_amdgcn_mfma_f32_16x16x32_bf16(af, bf, acc[j], 0, 0, 0);
    }
  }

#pragma unroll
  for (int j = 0; j < 4; ++j)
#pragma unroll
    for (int r = 0; r < 4; ++r) {
      int m = m0 + wave * 16 + quad * 4 + r;
      int n = n0 + j * 16 + ln;
      if constexpr (COUT_F32)
        ((float*)C)[(size_t)m * ldc + n] = acc[j][r];
      else
        ((u16*)C)[(size_t)m * ldc + n] = f2bf(acc[j][r]);
    }
}

// ---------------------------------------------------------------------------
// Fallback GEMM (fp32 staging) — used only if ws_size < 40 MiB.
// ---------------------------------------------------------------------------
template<bool F32>
__device__ __forceinline__ void stage8(u16* dst, const void* base, size_t off) {
  if constexpr (F32) {
    const float* p = (const float*)base + off;
    float4 a = *(const float4*)p;
    float4 b = *(const float4*)(p + 4);
    uint4 q;
    q.x = pkbf(a.x, a.y); q.y = pkbf(a.z, a.w);
    q.z = pkbf(b.x, b.y); q.w = pkbf(b.z, b.w);
    *(uint4*)dst = q;
  } else {
    *(uint4*)dst = *(const uint4*)((const u16*)base + off);
  }
}

template<bool AF32, bool BF32, bool COUT_F32, bool VSPLIT>
__global__ __launch_bounds__(256) void gemm_bt(
    const void* __restrict__ A, const void* __restrict__ B, void* __restrict__ C,
    u16* __restrict__ C2, int M, int N, int K, int ldc)
{
  __shared__ u16 As[128][40];
  __shared__ u16 Bs[128][40];
  const int tid  = threadIdx.x;
  const int wave = tid >> 6, lane = tid & 63;
  const int quad = lane >> 4, ln = lane & 15;
  const int m0 = blockIdx.y * 128, n0 = blockIdx.x * 128;
  const int wm = (wave >> 1) * 64, wn = (wave & 1) * 64;

  f32x4 acc[4][4] = {};

  for (int k0 = 0; k0 < K; k0 += 32) {
    __syncthreads();
#pragma unroll
    for (int i = 0; i < 2; ++i) {
      int idx = tid + i * 256;
      int row = idx >> 2, seg = (idx & 3) * 8;
      stage8<AF32>(&As[row][seg], A, (size_t)(m0 + row) * K + k0 + seg);
      stage8<BF32>(&Bs[row][seg], B, (size_t)(n0 + row) * K + k0 + seg);
    }
    __syncthreads();
    bf16x8 af[4], bfr[4];
#pragma unroll
    for (int i = 0; i < 4; ++i) af[i]  = *(const bf16x8*)&As[wm + i * 16 + ln][quad * 8];
#pragma unroll
    for (int j = 0; j < 4; ++j) bfr[j] = *(const bf16x8*)&Bs[wn + j * 16 + ln][quad * 8];
#pragma unroll
    for (int i = 0; i < 4; ++i)
#pragma unroll
      for (int j = 0; j < 4; ++j)
        acc[i][j] = __builtin_amdgcn_mfma_f32_16x16x32_bf16(af[i], bfr[j], acc[i][j], 0, 0, 0);
  }

  if constexpr (VSPLIT) {
    if (n0 >= 2048) {
      __shared__ u16 Cs[128][72];
#pragma unroll
      for (int c = 0; c < 2; ++c) {
        if ((wave >> 1) == c) {
#pragma unroll
          for (int i = 0; i < 4; ++i)
#pragma unroll
            for (int j = 0; j < 4; ++j)
#pragma unroll
              for (int r = 0; r < 4; ++r) {
                int pos = (i >> 1) * 32 + quad * 8 + (i & 1) * 4 + r;
                Cs[wn + j * 16 + ln][pos] = f2bf(acc[i][j][r]);
              }
        }
        __syncthreads();
        {
          int nl = tid >> 1, mseg = (tid & 1) * 32;
#pragma unroll
          for (int s2 = 0; s2 < 4; ++s2) {
            uint4 v4 = *(const uint4*)&Cs[nl][mseg + s2 * 8];
            *(uint4*)&C2[(size_t)(n0 - 2048 + nl) * 4096 + m0 + c * 64 + mseg + s2 * 8] = v4;
          }
        }
        __syncthreads();
      }
      return;
    }
  }

#pragma unroll
  for (int i = 0; i < 4; ++i)
#pragma unroll
    for (int j = 0; j < 4; ++j)
#pragma unroll
      for (int r = 0; r < 4; ++r) {
        int m = m0 + wm + i * 16 + quad * 4 + r;
        int n = n0 + wn + j * 16 + ln;
        if constexpr (COUT_F32)
          ((float*)C)[(size_t)m * ldc + n] = acc[i][j][r];
        else
          ((u16*)C)[(size_t)m * ldc + n] = f2bf(acc[i][j][r]);
      }
}

// ---------------------------------------------------------------------------
// Causal flash attention (MFMA), fixed-base softmax (linearly decomposable),
// transposed score path (S^T = K·Q^T, in-register P^T B-frag, O^T = V^T·P^T).
// Q-tile 128 (2 strips/wave), K-tile 64 processed as TWO 32-key subtiles
// (#pragma unroll 1) — register diet: live frags per subtile are kf[2][2] +
// vb[4] + sv[2] + p[2][4] + pb (~70 regs less than the monolithic body),
// targeting <=170 unified VGPR so min-waves 3 holds WITHOUT spilling
// (R12: cap128 -> 748 MB spill; R13: cap170+monolithic -> 145 MB spill;
// R14: cap256 clean at ~200 regs). Tripwire: WRITE_SIZE >> 20 MB = spill.
// SPLIT: grid 1024 = 32 qt x 2 key-halves x 16 heads, LPT; 3 blocks/CU with
// slot refill; writes bf16 unnormalized O-partial + fp32 l; combine2 ends.
// !SPLIT: grid 512, full range, normalized y.
// ---------------------------------------------------------------------------
struct StageRegs { uint4 k0, k1, v0, v1; };

__device__ __forceinline__ StageRegs attn_stage_load(
    const u16* __restrict__ qk, const u16* __restrict__ vT,
    int h, int kbase, int tid) {
  StageRegs s;
  {
    int key = tid >> 2, seg = (tid & 3) * 16;
    const u16* kp = qk + (size_t)(kbase + key) * 2048 + 1024 + h * 64 + seg;
    s.k0 = *(const uint4*)kp;
    s.k1 = *(const uint4*)(kp + 8);
  }
  {
    int kh = tid >> 7, d = (tid >> 1) & 63, sg = (tid & 1) * 16;
    const u16* vp = vT + (size_t)(h * 64 + d) * 4096 + kbase + kh * 32 + sg;
    s.v0 = *(const uint4*)vp;
    s.v1 = *(const uint4*)(vp + 8);
  }
  return s;
}

template<bool SPLIT>
__global__ __launch_bounds__(256, SPLIT ? 3 : 2) void attn_fwd(
    const u16* __restrict__ qk, const u16* __restrict__ vT,
    u16* __restrict__ out0, u16* __restrict__ out1,
    float* __restrict__ l0buf, float* __restrict__ l1buf)
{
  __shared__ u16 Ks[2][2][64][40];     // [buf][d-half][key][d%32] pad 40
  __shared__ u16 Vt[2][2][64][40];     // [buf][pi-key-half][d][pos%32]

  const int tid  = threadIdx.x;
  const int wave = tid >> 6, lane = tid & 63;
  const int quad = lane >> 4, ln = lane & 15;
  const int bx = blockIdx.x;
  int qt, h, ktb, kte;
  u16* oout; float* lout;
  if constexpr (SPLIT) {
    qt = 31 - (bx >> 5);               // heavy chunks (qt+1 iters) first
    int half = (bx >> 4) & 1;
    h = bx & 15;
    ktb = half ? (qt + 1) : 0;
    kte = half ? (2 * qt + 1) : qt;
    oout = half ? out1 : out0;
    lout = half ? l1buf : l0buf;
  } else {
    qt = (bx < 256) ? (31 - (bx >> 4)) : ((bx - 256) >> 4);
    h = bx & 15;
    ktb = 0; kte = 2 * qt + 1;
    oout = out0; lout = nullptr;
  }
  const float C1 = 0.18033688f;        // 0.125 * log2(e)

  const int sq0[2] = { qt * 128 + wave * 32, qt * 128 + wave * 32 + 16 };

  bf16x8 qa[2][2];
#pragma unroll
  for (int s = 0; s < 2; ++s) {
    const u16* qrow = qk + (size_t)(sq0[s] + ln) * 2048 + h * 64;
    qa[s][0] = *(const bf16x8*)(qrow + quad * 8);
    qa[s][1] = *(const bf16x8*)(qrow + 32 + quad * 8);
  }

  f32x4 o[2][4] = {};                  // O^T tiles: [strip][d-tile]; row=d, col=qrow
  float l_i[2] = {0.f, 0.f};           // per-lane partial l for qrow=ln

  StageRegs st = attn_stage_load(qk, vT, h, ktb * 64, tid);
  int b = 0;
  for (int kt = ktb; kt <= kte; ++kt, b ^= 1) {
    {
      int key = tid >> 2, seg = (tid & 3) * 16;
      int kh = seg >> 5, off = seg & 31;
      *(uint4*)&Ks[b][kh][key][off]     = st.k0;
      *(uint4*)&Ks[b][kh][key][off + 8] = st.k1;
      int vh = tid >> 7, d = (tid >> 1) & 63, sg = (tid & 1) * 16;
      *(uint4*)&Vt[b][vh][d][sg]     = st.v0;
      *(uint4*)&Vt[b][vh][d][sg + 8] = st.v1;
    }
    __syncthreads();
    if (kt < kte) st = attn_stage_load(qk, vT, h, (kt + 1) * 64, tid);

    bool act[2];
#pragma unroll
    for (int s = 0; s < 2; ++s) act[s] = (kt * 64 <= sq0[s] + 15);

    // two 32-key subtiles, real loop (unroll 1) to bound register pressure
#pragma unroll 1
    for (int s2 = 0; s2 < 2; ++s2) {
      bf16x8 kf[2][2], vb[4];
#pragma unroll
      for (int hf = 0; hf < 2; ++hf)
#pragma unroll
        for (int tp = 0; tp < 2; ++tp)
          kf[hf][tp] = *(const bf16x8*)&Ks[b][hf][(s2 * 2 + tp) * 16 + ln][quad * 8];
#pragma unroll
      for (int dt = 0; dt < 4; ++dt)
        vb[dt] = *(const bf16x8*)&Vt[b][s2][dt * 16 + ln][quad * 8];

#pragma unroll
      for (int s = 0; s < 2; ++s) {
        if (!act[s]) continue;         // wave-uniform
        f32x4 sv[2];
#pragma unroll
        for (int tp = 0; tp < 2; ++tp) {
          f32x4 z = {0.f, 0.f, 0.f, 0.f};
          z = __builtin_amdgcn_mfma_f32_16x16x32_bf16(kf[0][tp], qa[s][0], z, 0, 0, 0);
          z = __builtin_amdgcn_mfma_f32_16x16x32_bf16(kf[1][tp], qa[s][1], z, 0, 0, 0);
          sv[tp] = z;                  // row=key=(s2*2+tp)*16+quad*4+r, col=qrow=ln
        }
        float p[2][4];                 // [tp][r]
        if (kt * 64 + 63 > sq0[s]) {   // diagonal region: per-element causal mask
          const int qr = sq0[s] + ln;
#pragma unroll
          for (int tp = 0; tp < 2; ++tp) {
            int keyb = kt * 64 + (s2 * 2 + tp) * 16 + quad * 4;
#pragma unroll
            for (int r = 0; r < 4; ++r) {
              float arg = (keyb + r > qr) ? -200.0f : fmaf(sv[tp][r], C1, -46.0f);
              p[tp][r] = fexp2(arg);
            }
          }
        } else {
#pragma unroll
          for (int tp = 0; tp < 2; ++tp)
#pragma unroll
            for (int r = 0; r < 4; ++r)
              p[tp][r] = fexp2(fmaf(sv[tp][r], C1, -46.0f));
        }
        l_i[s] += ((p[0][0] + p[0][1]) + (p[0][2] + p[0][3]))
                + ((p[1][0] + p[1][1]) + (p[1][2] + p[1][3]));
        // P^T B-frag for this key-half (H == s2): slot j<4 -> p[0][j], j>=4 -> p[1][j-4]
        union { unsigned u[4]; bf16x8 v; } pk;
        pk.u[0] = pkbf(p[0][0], p[0][1]);
        pk.u[1] = pkbf(p[0][2], p[0][3]);
        pk.u[2] = pkbf(p[1][0], p[1][1]);
        pk.u[3] = pkbf(p[1][2], p[1][3]);
#pragma unroll
        for (int dt = 0; dt < 4; ++dt)
          o[s][dt] = __builtin_amdgcn_mfma_f32_16x16x32_bf16(vb[dt], pk.v, o[s][dt], 0, 0, 0);
      }
    }
  }

#pragma unroll
  for (int s = 0; s < 2; ++s) {
    l_i[s] += __shfl_xor(l_i[s], 16);
    l_i[s] += __shfl_xor(l_i[s], 32);
    int rowg = sq0[s] + ln;
    if constexpr (SPLIT) {
      // unnormalized bf16 partial + fp32 l partial (quad 0 stores l once)
#pragma unroll
      for (int dt = 0; dt < 4; ++dt)
#pragma unroll
        for (int r = 0; r < 4; ++r)
          oout[(size_t)rowg * 1024 + h * 64 + dt * 16 + quad * 4 + r] = f2bf(o[s][dt][r]);
      if (quad == 0) lout[rowg * 16 + h] = l_i[s];
    } else {
      float inv = 1.0f / l_i[s];
#pragma unroll
      for (int dt = 0; dt < 4; ++dt)
#pragma unroll
        for (int r = 0; r < 4; ++r)
          oout[(size_t)rowg * 1024 + h * 64 + dt * 16 + quad * 4 + r] = f2bf(o[s][dt][r] * inv);
    }
  }
}

extern "C" void kernel_launch(void* const* d_in, const int* in_sizes, int n_in,
                              void* d_out, int out_size, void* d_ws, size_t ws_size,
                              hipStream_t stream) {
  const float* x      = (const float*)d_in[0];   // [4096,1024] fp32
  const float* w_attn = (const float*)d_in[1];   // [3072,1024] fp32
  const float* w_proj = (const float*)d_in[2];   // [1024,1024] fp32

  char* ws = (char*)d_ws;
  u16* qk = (u16*)ws;                        // 16 MiB [4096][2048]
  u16* vT = (u16*)(ws + (16u << 20));        //  8 MiB [1024][4096] pi-permuted

  if (ws_size >= (size_t)(44u << 20)) {
    // Path A: key-split attention with partial combine. Peak 42.25 MiB.
    u16*   wpb = (u16*)(ws + (24u << 20));   //  2 MiB bf16 w_proj
    u16*   xb  = (u16*)(ws + (26u << 20));   //  8 MiB bf16 x       (dead after GEMM1)
    u16*   wab = (u16*)(ws + (34u << 20));   //  6 MiB bf16 w_attn  (dead after GEMM1)
    u16*   Op0 = (u16*)(ws + (26u << 20));   //  8 MiB bf16 O-partial half0 (overlays xb)
    u16*   Op1 = (u16*)(ws + (34u << 20));   //  8 MiB bf16 O-partial half1 (overlays wab + 2 MiB)
    float* l0  = (float*)(ws + (42u << 20));            // 256 KiB
    float* l1  = (float*)(ws + (42u << 20) + (256u << 10)); // 256 KiB
    u16*   y   = (u16*)ws;                   //  8 MiB, overlays qk (dead after attn)

    cvt3<<<4096, 256, 0, stream>>>(x, w_attn, w_proj, xb, wab, wpb);
    gemm_lds<false, true><<<dim3(24, 32), 256, 0, stream>>>(
        xb, wab, qk, vT, 4096, 3072, 1024, 2048);
    attn_fwd<true><<<dim3(1024), 256, 0, stream>>>(qk, vT, Op0, Op1, l0, l1);
    combine2<<<2048, 256, 0, stream>>>(Op0, Op1, l0, l1, y);
    gemm_t64<true><<<dim3(16, 64), 256, 0, stream>>>(
        y, wpb, d_out, 4096, 1024, 1024, 1024);
  } else if (ws_size >= (size_t)(40u << 20)) {
    // Path B: R11 behavior.
    u16* wpb = (u16*)(ws + (24u << 20));
    u16* xb  = (u16*)(ws + (26u << 20));
    u16* wab = (u16*)(ws + (34u << 20));
    u16* y   = (u16*)(ws + (26u << 20));

    cvt3<<<4096, 256, 0, stream>>>(x, w_attn, w_proj, xb, wab, wpb);
    gemm_lds<false, true><<<dim3(24, 32), 256, 0, stream>>>(
        xb, wab, qk, vT, 4096, 3072, 1024, 2048);
    attn_fwd<false><<<dim3(512), 256, 0, stream>>>(qk, vT, y, nullptr, nullptr, nullptr);
    gemm_t64<true><<<dim3(16, 64), 256, 0, stream>>>(
        y, wpb, d_out, 4096, 1024, 1024, 1024);
  } else {
    // Path C: fp32-staging fallback.
    u16* y = (u16*)(ws + (24u << 20));
    gemm_bt<true, true, false, true><<<dim3(24, 32), 256, 0, stream>>>(
        x, w_attn, qk, vT, 4096, 3072, 1024, 2048);
    attn_fwd<false><<<dim3(512), 256, 0, stream>>>(qk, vT, y, nullptr, nullptr, nullptr);
    gemm_bt<false, true, true, false><<<dim3(8, 32), 256, 0, stream>>>(
        y, w_proj, d_out, nullptr, 4096, 1024, 1024, 1024);
  }
}